// Round 3
// baseline (959.483 us; speedup 1.0000x reference)
//
#include <hip/hip_runtime.h>
#include <math.h>

// ---- problem constants ----
constexpr int Bc = 4, Lc = 2048, Kc = 30;
constexpr int Nn = Bc * Lc;            // 8192 nodes
constexpr int NSc = 1024, NVc = 256;
constexpr int NEc = Nn * Kc;           // 245760 edges
constexpr int SK = 263;                // 7 + 256 scalar GVP input dim

// ---- d_out float offsets (outputs concatenated flat in return order) ----
constexpr size_t OUT_NS = 0;                                  // (8192,1024)
constexpr size_t OUT_NV = (size_t)Nn * NSc;                   // (8192,256,3)
constexpr size_t OUT_ES = OUT_NV + (size_t)Nn * NVc * 3;      // (245760,32)
constexpr size_t OUT_EV = OUT_ES + (size_t)NEc * 32;          // (245760,1,3)
constexpr size_t OUT_EI = OUT_EV + (size_t)NEc * 3;           // (2,245760) as float

// ---- workspace float offsets ----
constexpr size_t WS_SIN = 0;                                  // (8192,263) s_in
constexpr size_t WS_NDV = WS_SIN + (size_t)Nn * SK;           // (8192,9) node_v
constexpr size_t WS_EIX = WS_NDV + (size_t)Nn * 9;            // (245760) int E_idx
constexpr size_t WS_EDS = WS_EIX + (size_t)NEc;               // (245760) E_dist
constexpr size_t WS_SUM = WS_EDS + (size_t)NEc;               // (4,4) batch sums
constexpr size_t WS_CMF = WS_SUM + 16;                        // (8192) canonical coord_mask float

__device__ __forceinline__ void norml3(float& x, float& y, float& z) {
  float ss = x*x + y*y + z*z;
  float inv = 1.0f / sqrtf(ss + 1e-8f);
  x *= inv; y *= inv; z *= inv;
}

// ---------------- Kernel M: canonicalize coord_mask (bytes-vs-int32 autodetect) ----
// If source is a bool-byte array, bytes at p%4!=0 are random 0/1 (some nonzero,
// P[all zero]=2^-6144). If it's int32 0/1, those bytes are all zero.
__global__ __launch_bounds__(1024) void kmask(const unsigned char* __restrict__ cm,
                                              float* __restrict__ ws) {
  __shared__ int flag;
  if (threadIdx.x == 0) flag = 0;
  __syncthreads();
  int any = 0;
  for (int p = threadIdx.x; p < Nn; p += 1024)
    if (p & 3) any |= cm[p];
  if (any) atomicOr(&flag, 1);
  __syncthreads();
  bool bytefmt = (flag != 0);
  float* cmf = ws + WS_CMF;
  for (int n = threadIdx.x; n < Nn; n += 1024) {
    unsigned char v = bytefmt ? cm[n] : cm[4*n];  // LE low byte of int32 0/1
    cmf[n] = v ? 1.f : 0.f;
  }
}

// ---------------- Kernel A: per-node geometric features ----------------
__global__ __launch_bounds__(256) void knode_geom(const float* __restrict__ coords,
                                                  float* __restrict__ ws) {
  int n = blockIdx.x * 256 + threadIdx.x;
  if (n >= Nn) return;
  int b = n / Lc, l = n % Lc;
  const float* Xb = coords + (size_t)b * Lc * 9;
  float ax[7][3];
  #pragma unroll
  for (int m = 0; m < 7; ++m) {
    int t = 3*l + m - 2;
    if (t >= 0 && t < 3*Lc) { ax[m][0]=Xb[t*3+0]; ax[m][1]=Xb[t*3+1]; ax[m][2]=Xb[t*3+2]; }
    else { ax[m][0]=0.f; ax[m][1]=0.f; ax[m][2]=0.f; }
  }
  float U[5][3];
  #pragma unroll
  for (int mi = 0; mi < 5; ++mi) {
    int t = 3*l - 1 + mi;
    if (t >= 0 && t <= 3*Lc - 2) {
      float x = ax[mi+2][0]-ax[mi+1][0], y = ax[mi+2][1]-ax[mi+1][1], z = ax[mi+2][2]-ax[mi+1][2];
      norml3(x,y,z);
      U[mi][0]=x; U[mi][1]=y; U[mi][2]=z;
    } else { U[mi][0]=0.f; U[mi][1]=0.f; U[mi][2]=0.f; }
  }
  float cph[3], sph[3];
  #pragma unroll
  for (int a = 0; a < 3; ++a) {
    int t = 3*l + a - 1;
    if (t < 0 || t > 3*Lc - 4) { cph[a] = 1.f; sph[a] = 0.f; continue; }
    const float *u2 = U[a], *u1 = U[a+1], *u0 = U[a+2];
    float n2x = u2[1]*u1[2]-u2[2]*u1[1], n2y = u2[2]*u1[0]-u2[0]*u1[2], n2z = u2[0]*u1[1]-u2[1]*u1[0];
    norml3(n2x,n2y,n2z);
    float n1x = u1[1]*u0[2]-u1[2]*u0[1], n1y = u1[2]*u0[0]-u1[0]*u0[2], n1z = u1[0]*u0[1]-u1[1]*u0[0];
    norml3(n1x,n1y,n1z);
    float cd = n2x*n1x + n2y*n1y + n2z*n1z;
    cd = fminf(fmaxf(cd, -1.f + 1e-7f), 1.f - 1e-7f);
    float dt = u2[0]*n1x + u2[1]*n1y + u2[2]*n1z;
    float sg = (dt > 0.f) ? 1.f : ((dt < 0.f) ? -1.f : 0.f);
    float D = sg * acosf(cd);
    cph[a] = cosf(D); sph[a] = sinf(D);
  }
  float fx=0.f,fy=0.f,fz=0.f, kx=0.f,ky=0.f,kz=0.f;
  if (l < Lc-1) { fx=ax[6][0]-ax[3][0]; fy=ax[6][1]-ax[3][1]; fz=ax[6][2]-ax[3][2]; norml3(fx,fy,fz); }
  if (l > 0)    { kx=ax[0][0]-ax[3][0]; ky=ax[0][1]-ax[3][1]; kz=ax[0][2]-ax[3][2]; norml3(kx,ky,kz); }
  float cx=ax[4][0]-ax[3][0], cy=ax[4][1]-ax[3][1], cz=ax[4][2]-ax[3][2]; norml3(cx,cy,cz);
  float nx=ax[2][0]-ax[3][0], ny=ax[2][1]-ax[3][1], nz=ax[2][2]-ax[3][2]; norml3(nx,ny,nz);
  float bix=cx+nx, biy=cy+ny, biz=cz+nz; norml3(bix,biy,biz);
  float px=cy*nz-cz*ny, py=cz*nx-cx*nz, pz=cx*ny-cy*nx; norml3(px,py,pz);
  const float c1 = 0.57735026f, c2 = 0.81649658f;
  float sx = -bix*c1 - px*c2, sy = -biy*c1 - py*c2, sz = -biz*c1 - pz*c2;

  float cmf = ws[WS_CMF + n];
  float* sr = ws + WS_SIN + (size_t)n * SK;
  sr[0]=cph[0]; sr[1]=cph[1]; sr[2]=cph[2]; sr[3]=sph[0]; sr[4]=sph[1]; sr[5]=sph[2]; sr[6]=cmf;
  float* vr = ws + WS_NDV + (size_t)n * 9;
  vr[0]=fx; vr[1]=fy; vr[2]=fz; vr[3]=kx; vr[4]=ky; vr[5]=kz; vr[6]=sx; vr[7]=sy; vr[8]=sz;
}

// ---------------- Kernel D1: vh = wh^T * node_v ; vn -> s_in[7..262] ----------------
__global__ __launch_bounds__(256) void kgvp_pre(float* __restrict__ ws,
                                                const float* __restrict__ wh,
                                                float* __restrict__ avh) {
  int n = blockIdx.x, h = threadIdx.x;
  const float* v = ws + WS_NDV + (size_t)n * 9;
  float w0 = wh[h], w1 = wh[256+h], w2 = wh[512+h];
  float vh0 = v[0]*w0 + v[3]*w1 + v[6]*w2;
  float vh1 = v[1]*w0 + v[4]*w1 + v[7]*w2;
  float vh2 = v[2]*w0 + v[5]*w1 + v[8]*w2;
  avh[(size_t)0*Nn*256 + (size_t)n*256 + h] = vh0;
  avh[(size_t)1*Nn*256 + (size_t)n*256 + h] = vh1;
  avh[(size_t)2*Nn*256 + (size_t)n*256 + h] = vh2;
  ws[WS_SIN + (size_t)n*SK + 7 + h] = sqrtf(fmaxf(vh0*vh0 + vh1*vh1 + vh2*vh2, 1e-8f));
}

// ---------------- Kernel B: exact kNN top-30 per (b,i) row — exact-f32 ordering ----
// key = (float_bits(D_adjust)<<32)|j reproduces top_k order incl. lowest-index ties.
__global__ __launch_bounds__(256) void ktopk(const float* __restrict__ coords,
                                             const int* __restrict__ resid,
                                             const unsigned char* __restrict__ pmask,
                                             float* __restrict__ ws) {
  __shared__ float xs[Lc*3];
  __shared__ float cms[Lc];
  __shared__ float rms[Lc];
  __shared__ int   res[Lc];
  __shared__ unsigned long long warr[4];
  __shared__ unsigned long long winsh;
  int row = blockIdx.x;
  int b = row / Lc, i = row % Lc;
  int tid = threadIdx.x;
  const float* Xb = coords + (size_t)b * Lc * 9;
  for (int j = tid; j < Lc; j += 256) {
    xs[j*3+0] = Xb[j*9+3]; xs[j*3+1] = Xb[j*9+4]; xs[j*3+2] = Xb[j*9+5];
    cms[j] = ws[WS_CMF + b*Lc + j];
    rms[j] = pmask[b*Lc+j] ? 0.f : 1.f;   // all-False input: safe either layout
    res[j] = resid[b*Lc+j];
  }
  __syncthreads();
  float xi0 = xs[i*3+0], xi1 = xs[i*3+1], xi2 = xs[i*3+2];
  float cmi = cms[i], rmi = rms[i];
  int ri = res[i];
  unsigned long long key[8];
  #pragma unroll
  for (int m = 0; m < 8; ++m) {
    int j = tid + 256*m;
    float dx = __fsub_rn(xi0, xs[j*3+0]);
    float dy = __fsub_rn(xi1, xs[j*3+1]);
    float dz = __fsub_rn(xi2, xs[j*3+2]);
    float ss = __fadd_rn(__fadd_rn(__fmul_rn(dx,dx), __fmul_rn(dy,dy)), __fmul_rn(dz,dz));
    float dist = __fsqrt_rn(__fadd_rn(ss, 1e-8f));
    float cm2 = __fmul_rn(cmi, cms[j]);
    float D = __fmul_rn(cm2, dist);
    int ad = ri - res[j]; ad = ad < 0 ? -ad : ad;
    float covm = (ad <= 3) ? 0.f : 1.f;                 // (1 - cov)
    float dseq = (float)(i >= j ? i - j : j - i);
    float t1 = __fmul_rn(__fsub_rn(1.f, cm2), __fadd_rn(1e8f, __fmul_rn(dseq, 1e6f)));
    float rm2 = __fmul_rn(rmi, rms[j]);
    float t2 = __fmul_rn(__fsub_rn(1.f, rm2), 1e10f);
    float adj = __fadd_rn(__fadd_rn(__fmul_rn(D, covm), t1), t2);
    key[m] = ((unsigned long long)__float_as_uint(adj) << 32) | (unsigned int)j;
  }
  int lane = tid & 63, wid = tid >> 6;
  float svx = 0.f, svy = 0.f, svz = 0.f, scn = 0.f;
  int* eix = (int*)(ws + WS_EIX);
  for (int r = 0; r < Kc; ++r) {
    unsigned long long mk = key[0];
    #pragma unroll
    for (int m = 1; m < 8; ++m) mk = key[m] < mk ? key[m] : mk;
    #pragma unroll
    for (int off = 32; off > 0; off >>= 1) {
      unsigned long long o = __shfl_down(mk, off);
      mk = o < mk ? o : mk;
    }
    if (lane == 0) warr[wid] = mk;
    __syncthreads();
    if (tid == 0) {
      unsigned long long w01 = warr[0] < warr[1] ? warr[0] : warr[1];
      unsigned long long w23 = warr[2] < warr[3] ? warr[2] : warr[3];
      winsh = w01 < w23 ? w01 : w23;
    }
    __syncthreads();
    unsigned long long w = winsh;
    int jw = (int)(w & 0xffffffffULL);
    if ((jw & 255) == tid) key[jw >> 8] = ~0ULL;  // remove winner
    if (tid == 0) {
      float dx = __fsub_rn(xi0, xs[jw*3+0]);
      float dy = __fsub_rn(xi1, xs[jw*3+1]);
      float dz = __fsub_rn(xi2, xs[jw*3+2]);
      float ss = __fadd_rn(__fadd_rn(__fmul_rn(dx,dx), __fmul_rn(dy,dy)), __fmul_rn(dz,dz));
      float dist = __fsqrt_rn(__fadd_rn(ss, 1e-8f));
      float cm2 = __fmul_rn(cmi, cms[jw]);
      float D = __fmul_rn(cm2, dist);
      eix[(size_t)row*Kc + r] = jw;
      ws[WS_EDS + (size_t)row*Kc + r] = D;
      float ecm = (D < 5e7f) ? 1.f : 0.f;
      svx += dx * ecm; svy += dy * ecm; svz += dz * ecm; scn += ecm;
    }
  }
  if (tid == 0) {
    atomicAdd(&ws[WS_SUM + b*4 + 0], svx);
    atomicAdd(&ws[WS_SUM + b*4 + 1], svy);
    atomicAdd(&ws[WS_SUM + b*4 + 2], svz);
    atomicAdd(&ws[WS_SUM + b*4 + 3], scn);
  }
}

// ---------------- Kernel D2: S GEMM (8192x263)@(263x1024)+bias -> ns region ----------------
__global__ __launch_bounds__(256) void kgemm_s(const float* __restrict__ ws,
                                               const float* __restrict__ wsw,
                                               const float* __restrict__ wsb,
                                               float* __restrict__ out) {
  __shared__ float A[16][SK+1];
  int tid = threadIdx.x;
  int row0 = blockIdx.x * 16;
  for (int r = 0; r < 16; ++r)
    for (int k = tid; k < SK; k += 256)
      A[r][k] = ws[WS_SIN + (size_t)(row0+r)*SK + k];
  __syncthreads();
  float acc[16][4];
  #pragma unroll
  for (int r = 0; r < 16; ++r) { acc[r][0]=0.f; acc[r][1]=0.f; acc[r][2]=0.f; acc[r][3]=0.f; }
  for (int k = 0; k < SK; ++k) {
    float b0 = wsw[(size_t)k*NSc + tid];
    float b1 = wsw[(size_t)k*NSc + tid + 256];
    float b2 = wsw[(size_t)k*NSc + tid + 512];
    float b3 = wsw[(size_t)k*NSc + tid + 768];
    #pragma unroll
    for (int r = 0; r < 16; ++r) {
      float a = A[r][k];
      acc[r][0] = fmaf(a, b0, acc[r][0]);
      acc[r][1] = fmaf(a, b1, acc[r][1]);
      acc[r][2] = fmaf(a, b2, acc[r][2]);
      acc[r][3] = fmaf(a, b3, acc[r][3]);
    }
  }
  float bb0 = wsb[tid], bb1 = wsb[tid+256], bb2 = wsb[tid+512], bb3 = wsb[tid+768];
  for (int r = 0; r < 16; ++r) {
    size_t o = OUT_NS + (size_t)(row0+r)*NSc + tid;
    out[o]     = acc[r][0] + bb0;
    out[o+256] = acc[r][1] + bb1;
    out[o+512] = acc[r][2] + bb2;
    out[o+768] = acc[r][3] + bb3;
  }
}

// ---------------- Kernel D3: V GEMM per d: (8192x256)@(256x256) -> nv region ----------------
__global__ __launch_bounds__(256) void kgemm_v(const float* __restrict__ avh,
                                               const float* __restrict__ wv,
                                               float* __restrict__ out) {
  int d = blockIdx.y;
  int row0 = blockIdx.x * 16;
  int tid = threadIdx.x;
  __shared__ float A[16][257];
  const float* Ad = avh + (size_t)d * Nn * 256;
  for (int r = 0; r < 16; ++r) A[r][tid] = Ad[(size_t)(row0+r)*256 + tid];
  __syncthreads();
  float acc[16];
  #pragma unroll
  for (int r = 0; r < 16; ++r) acc[r] = 0.f;
  for (int k = 0; k < 256; ++k) {
    float bb = wv[(size_t)k*256 + tid];
    #pragma unroll
    for (int r = 0; r < 16; ++r) acc[r] = fmaf(A[r][k], bb, acc[r]);
  }
  for (int r = 0; r < 16; ++r)
    out[OUT_NV + (size_t)(row0+r)*768 + (size_t)tid*3 + d] = acc[r];
}

// ---------------- Kernel C: edge features + edge GVP + edge LN + ei ----------------
__global__ __launch_bounds__(256) void kedge(const float* __restrict__ coords,
    const int* __restrict__ resid,
    const float* __restrict__ ewh, const float* __restrict__ eww,
    const float* __restrict__ ewb, const float* __restrict__ ewv,
    const float* __restrict__ elg, const float* __restrict__ elb,
    const float* __restrict__ ws, float* __restrict__ out) {
  __shared__ float w[35*32];
  __shared__ float wb[32], g[32], bb[32];
  int tid = threadIdx.x;
  for (int t = tid; t < 35*32; t += 256) w[t] = eww[t];
  if (tid < 32) { wb[tid] = ewb[tid]; g[tid] = elg[tid]; bb[tid] = elb[tid]; }
  __syncthreads();
  int e = blockIdx.x * 256 + tid;
  if (e >= NEc) return;
  int b = e / (Lc*Kc);
  int rem = e - b*(Lc*Kc);
  int i = rem / Kc;
  int row = b*Lc + i;
  const int* eix = (const int*)(ws + WS_EIX);
  int j = eix[e];
  float Dn = ws[WS_EDS + e];
  float ecm = (Dn < 5e7f) ? 1.f : 0.f;
  bool valid = (Dn < 5e9f) && (Dn < 5e7f);
  int dcl = resid[row] - resid[b*Lc + j];
  dcl = dcl < -32 ? -32 : (dcl > 32 ? 32 : dcl);
  float dpos = (float)dcl;
  float s[35];
  #pragma unroll
  for (int m = 0; m < 16; ++m) {
    float c = (20.f/15.f) * (float)m;
    float z = (Dn - c) * 0.8f;
    s[m] = expf(-z*z);
  }
  #pragma unroll
  for (int m = 0; m < 8; ++m) {
    float fr = expf((float)(2*m) * (-0.57564627324851148f));
    float ang = dpos * fr;
    s[16+m] = cosf(ang);
    s[24+m] = sinf(ang);
  }
  float csf = ws[WS_CMF + row];
  float cdf = ws[WS_CMF + b*Lc + j];
  s[32] = 1.f - csf; s[33] = 1.f - cdf;
  const float* Xb = coords + (size_t)b*Lc*9;
  float vx = Xb[i*9+3] - Xb[j*9+3];
  float vy = Xb[i*9+4] - Xb[j*9+4];
  float vz = Xb[i*9+5] - Xb[j*9+5];
  float cnt = ws[WS_SUM + b*4 + 3];
  float mx = ws[WS_SUM + b*4 + 0] / cnt;
  float my = ws[WS_SUM + b*4 + 1] / cnt;
  float mz = ws[WS_SUM + b*4 + 2] / cnt;
  float om = 1.f - ecm;
  vx = vx*ecm + mx*om; vy = vy*ecm + my*om; vz = vz*ecm + mz*om;
  float ss2 = vx*vx + vy*vy + vz*vz;
  float inv = 1.f / sqrtf(ss2 + 1e-8f);
  float e0 = vx*inv, e1 = vy*inv, e2 = vz*inv;
  if (!isfinite(e0)) e0 = 0.f;
  if (!isfinite(e1)) e1 = 0.f;
  if (!isfinite(e2)) e2 = 0.f;
  float wh00 = ewh[0], wv00 = ewv[0];
  float vh0 = e0*wh00, vh1 = e1*wh00, vh2 = e2*wh00;
  s[34] = sqrtf(fmaxf(vh0*vh0 + vh1*vh1 + vh2*vh2, 1e-8f));
  float o[32]; float sm = 0.f;
  #pragma unroll
  for (int c = 0; c < 32; ++c) {
    float a = wb[c];
    #pragma unroll
    for (int q = 0; q < 35; ++q) a = fmaf(s[q], w[q*32 + c], a);
    o[c] = a; sm += a;
  }
  float mu = sm * (1.f/32.f);
  float sq = 0.f;
  #pragma unroll
  for (int c = 0; c < 32; ++c) { float dd = o[c]-mu; sq += dd*dd; }
  float isd = 1.f / sqrtf(sq*(1.f/32.f) + 1e-4f);
  float vo0 = vh0*wv00, vo1 = vh1*wv00, vo2 = vh2*wv00;
  float vn2 = fmaxf(vo0*vo0 + vo1*vo1 + vo2*vo2, 1e-8f);
  float ivn = 1.f / sqrtf(vn2);
  float fv = valid ? 1.f : 0.f;
  #pragma unroll
  for (int c = 0; c < 32; ++c)
    out[OUT_ES + (size_t)e*32 + c] = fv * ((o[c]-mu)*isd*g[c] + bb[c]);
  out[OUT_EV + (size_t)e*3 + 0] = fv * (vo0*ivn);
  out[OUT_EV + (size_t)e*3 + 1] = fv * (vo1*ivn);
  out[OUT_EV + (size_t)e*3 + 2] = fv * (vo2*ivn);
  out[OUT_EI + e]       = valid ? (float)row          : -1.f;
  out[OUT_EI + NEc + e] = valid ? (float)(b*Lc + j)   : -1.f;
}

// ---------------- Kernel D4: node LayerNorm + confidence RBF term ----------------
__global__ __launch_bounds__(256) void kln_node(const float* __restrict__ conf,
    const float* __restrict__ cw, const float* __restrict__ cb,
    const float* __restrict__ lg, const float* __restrict__ lb,
    float* __restrict__ out) {
  int n = blockIdx.x, tid = threadIdx.x;
  size_t base = OUT_NS + (size_t)n*NSc;
  float x0 = out[base + tid];
  float x1 = out[base + tid + 256];
  float x2 = out[base + tid + 512];
  float x3 = out[base + tid + 768];
  float sm = x0+x1+x2+x3;
  float sq = x0*x0+x1*x1+x2*x2+x3*x3;
  int lane = tid & 63, wid = tid >> 6;
  #pragma unroll
  for (int off = 32; off > 0; off >>= 1) { sm += __shfl_down(sm, off); sq += __shfl_down(sq, off); }
  __shared__ float rs[4], rq[4];
  if (lane == 0) { rs[wid] = sm; rq[wid] = sq; }
  __syncthreads();
  sm = rs[0]+rs[1]+rs[2]+rs[3];
  sq = rq[0]+rq[1]+rq[2]+rq[3];
  float mu = sm * (1.f/1024.f);
  float var = fmaxf(sq * (1.f/1024.f) - mu*mu, 0.f);
  float isd = 1.f / sqrtf(var + 1e-4f);
  float cf = conf[n];
  float rb[16];
  #pragma unroll
  for (int m = 0; m < 16; ++m) {
    float z = (cf - (float)m*(1.f/15.f)) * 16.f;
    rb[m] = expf(-z*z);
  }
  float xs_[4] = {x0, x1, x2, x3};
  #pragma unroll
  for (int q = 0; q < 4; ++q) {
    int c = tid + q*256;
    float t = cb[c];
    #pragma unroll
    for (int m = 0; m < 16; ++m) t = fmaf(rb[m], cw[m*1024 + c], t);
    out[base + c] = (xs_[q]-mu)*isd*lg[c] + lb[c] + t;
  }
}

// ---------------- Kernel D5: node vector norm epilogue ----------------
__global__ __launch_bounds__(256) void kvnorm(float* __restrict__ out) {
  int n = blockIdx.x, tid = threadIdx.x;
  size_t base = OUT_NV + (size_t)n*768;
  float v0 = out[base + tid*3 + 0];
  float v1 = out[base + tid*3 + 1];
  float v2 = out[base + tid*3 + 2];
  float vn2 = fmaxf(v0*v0 + v1*v1 + v2*v2, 1e-8f);
  int lane = tid & 63, wid = tid >> 6;
  float sm = vn2;
  #pragma unroll
  for (int off = 32; off > 0; off >>= 1) sm += __shfl_down(sm, off);
  __shared__ float rs[4];
  if (lane == 0) rs[wid] = sm;
  __syncthreads();
  sm = rs[0]+rs[1]+rs[2]+rs[3];
  float isd = 1.f / sqrtf(sm * (1.f/256.f));
  out[base + tid*3 + 0] = v0*isd;
  out[base + tid*3 + 1] = v1*isd;
  out[base + tid*3 + 2] = v2*isd;
}

extern "C" void kernel_launch(void* const* d_in, const int* in_sizes, int n_in,
                              void* d_out, int out_size, void* d_ws, size_t ws_size,
                              hipStream_t stream) {
  const float* coords         = (const float*)d_in[0];
  const unsigned char* cmask  = (const unsigned char*)d_in[1];
  const int* resid            = (const int*)d_in[2];
  const unsigned char* pmask  = (const unsigned char*)d_in[3];
  const float* conf           = (const float*)d_in[4];
  const float* nwh            = (const float*)d_in[5];
  const float* nww            = (const float*)d_in[6];
  const float* nwb            = (const float*)d_in[7];
  const float* nwv            = (const float*)d_in[8];
  const float* nlg            = (const float*)d_in[9];
  const float* nlb            = (const float*)d_in[10];
  const float* ewh            = (const float*)d_in[11];
  const float* eww            = (const float*)d_in[12];
  const float* ewb            = (const float*)d_in[13];
  const float* ewv            = (const float*)d_in[14];
  const float* elg            = (const float*)d_in[15];
  const float* elb            = (const float*)d_in[16];
  const float* cw             = (const float*)d_in[17];
  const float* cb             = (const float*)d_in[18];
  float* out = (float*)d_out;
  float* ws  = (float*)d_ws;
  float* avh = out + OUT_ES;   // stage vh in es output region; consumed before kedge writes es

  hipMemsetAsync((void*)(ws + WS_SUM), 0, 16*sizeof(float), stream);
  kmask<<<1, 1024, 0, stream>>>(cmask, ws);
  knode_geom<<<(Nn+255)/256, 256, 0, stream>>>(coords, ws);
  kgvp_pre<<<Nn, 256, 0, stream>>>(ws, nwh, avh);
  ktopk<<<Nn, 256, 0, stream>>>(coords, resid, pmask, ws);
  kgemm_s<<<Nn/16, 256, 0, stream>>>(ws, nww, nwb, out);
  kgemm_v<<<dim3(Nn/16, 3), 256, 0, stream>>>(avh, nwv, out);
  kedge<<<NEc/256, 256, 0, stream>>>(coords, resid, ewh, eww, ewb, ewv, elg, elb, ws, out);
  kln_node<<<Nn, 256, 0, stream>>>(conf, cw, cb, nlg, nlb, out);
  kvnorm<<<Nn, 256, 0, stream>>>(out);
}

// Round 4
// 605.960 us; speedup vs baseline: 1.5834x; 1.5834x over previous
//
#include <hip/hip_runtime.h>
#include <math.h>

// ---- problem constants ----
constexpr int Bc = 4, Lc = 2048, Kc = 30;
constexpr int Nn = Bc * Lc;            // 8192 nodes
constexpr int NSc = 1024, NVc = 256;
constexpr int NEc = Nn * Kc;           // 245760 edges
constexpr int SK = 263;                // 7 + 256 scalar GVP input dim

// ---- d_out float offsets (outputs concatenated flat in return order) ----
constexpr size_t OUT_NS = 0;                                  // (8192,1024)
constexpr size_t OUT_NV = (size_t)Nn * NSc;                   // (8192,256,3)
constexpr size_t OUT_ES = OUT_NV + (size_t)Nn * NVc * 3;      // (245760,32)
constexpr size_t OUT_EV = OUT_ES + (size_t)NEc * 32;          // (245760,1,3)
constexpr size_t OUT_EI = OUT_EV + (size_t)NEc * 3;           // (2,245760) as float

// ---- workspace float offsets ----
constexpr size_t WS_SIN = 0;                                  // (8192,263) s_in
constexpr size_t WS_NDV = WS_SIN + (size_t)Nn * SK;           // (8192,9) node_v
constexpr size_t WS_EIX = WS_NDV + (size_t)Nn * 9;            // (245760) int E_idx
constexpr size_t WS_EDS = WS_EIX + (size_t)NEc;               // (245760) E_dist
constexpr size_t WS_CMF = WS_EDS + (size_t)NEc;               // (8192) canonical coord_mask float

__device__ __forceinline__ void norml3(float& x, float& y, float& z) {
  float ss = x*x + y*y + z*z;
  float inv = 1.0f / sqrtf(ss + 1e-8f);
  x *= inv; y *= inv; z *= inv;
}

// ---------------- Kernel M: canonicalize coord_mask (bytes-vs-int32 autodetect) ----
__global__ __launch_bounds__(1024) void kmask(const unsigned char* __restrict__ cm,
                                              float* __restrict__ ws) {
  __shared__ int flag;
  if (threadIdx.x == 0) flag = 0;
  __syncthreads();
  int any = 0;
  for (int p = threadIdx.x; p < Nn; p += 1024)
    if (p & 3) any |= cm[p];
  if (any) atomicOr(&flag, 1);
  __syncthreads();
  bool bytefmt = (flag != 0);
  float* cmf = ws + WS_CMF;
  for (int n = threadIdx.x; n < Nn; n += 1024) {
    unsigned char v = bytefmt ? cm[n] : cm[4*n];  // LE low byte of int32 0/1
    cmf[n] = v ? 1.f : 0.f;
  }
}

// ---------------- Kernel A: per-node geometric features ----------------
__global__ __launch_bounds__(256) void knode_geom(const float* __restrict__ coords,
                                                  float* __restrict__ ws) {
  int n = blockIdx.x * 256 + threadIdx.x;
  if (n >= Nn) return;
  int b = n / Lc, l = n % Lc;
  const float* Xb = coords + (size_t)b * Lc * 9;
  float ax[7][3];
  #pragma unroll
  for (int m = 0; m < 7; ++m) {
    int t = 3*l + m - 2;
    if (t >= 0 && t < 3*Lc) { ax[m][0]=Xb[t*3+0]; ax[m][1]=Xb[t*3+1]; ax[m][2]=Xb[t*3+2]; }
    else { ax[m][0]=0.f; ax[m][1]=0.f; ax[m][2]=0.f; }
  }
  float U[5][3];
  #pragma unroll
  for (int mi = 0; mi < 5; ++mi) {
    int t = 3*l - 1 + mi;
    if (t >= 0 && t <= 3*Lc - 2) {
      float x = ax[mi+2][0]-ax[mi+1][0], y = ax[mi+2][1]-ax[mi+1][1], z = ax[mi+2][2]-ax[mi+1][2];
      norml3(x,y,z);
      U[mi][0]=x; U[mi][1]=y; U[mi][2]=z;
    } else { U[mi][0]=0.f; U[mi][1]=0.f; U[mi][2]=0.f; }
  }
  float cph[3], sph[3];
  #pragma unroll
  for (int a = 0; a < 3; ++a) {
    int t = 3*l + a - 1;
    if (t < 0 || t > 3*Lc - 4) { cph[a] = 1.f; sph[a] = 0.f; continue; }
    const float *u2 = U[a], *u1 = U[a+1], *u0 = U[a+2];
    float n2x = u2[1]*u1[2]-u2[2]*u1[1], n2y = u2[2]*u1[0]-u2[0]*u1[2], n2z = u2[0]*u1[1]-u2[1]*u1[0];
    norml3(n2x,n2y,n2z);
    float n1x = u1[1]*u0[2]-u1[2]*u0[1], n1y = u1[2]*u0[0]-u1[0]*u0[2], n1z = u1[0]*u0[1]-u1[1]*u0[0];
    norml3(n1x,n1y,n1z);
    float cd = n2x*n1x + n2y*n1y + n2z*n1z;
    cd = fminf(fmaxf(cd, -1.f + 1e-7f), 1.f - 1e-7f);
    float dt = u2[0]*n1x + u2[1]*n1y + u2[2]*n1z;
    float sg = (dt > 0.f) ? 1.f : ((dt < 0.f) ? -1.f : 0.f);
    float D = sg * acosf(cd);
    cph[a] = cosf(D); sph[a] = sinf(D);
  }
  float fx=0.f,fy=0.f,fz=0.f, kx=0.f,ky=0.f,kz=0.f;
  if (l < Lc-1) { fx=ax[6][0]-ax[3][0]; fy=ax[6][1]-ax[3][1]; fz=ax[6][2]-ax[3][2]; norml3(fx,fy,fz); }
  if (l > 0)    { kx=ax[0][0]-ax[3][0]; ky=ax[0][1]-ax[3][1]; kz=ax[0][2]-ax[3][2]; norml3(kx,ky,kz); }
  float cx=ax[4][0]-ax[3][0], cy=ax[4][1]-ax[3][1], cz=ax[4][2]-ax[3][2]; norml3(cx,cy,cz);
  float nx=ax[2][0]-ax[3][0], ny=ax[2][1]-ax[3][1], nz=ax[2][2]-ax[3][2]; norml3(nx,ny,nz);
  float bix=cx+nx, biy=cy+ny, biz=cz+nz; norml3(bix,biy,biz);
  float px=cy*nz-cz*ny, py=cz*nx-cx*nz, pz=cx*ny-cy*nx; norml3(px,py,pz);
  const float c1 = 0.57735026f, c2 = 0.81649658f;
  float sx = -bix*c1 - px*c2, sy = -biy*c1 - py*c2, sz = -biz*c1 - pz*c2;

  float cmf = ws[WS_CMF + n];
  float* sr = ws + WS_SIN + (size_t)n * SK;
  sr[0]=cph[0]; sr[1]=cph[1]; sr[2]=cph[2]; sr[3]=sph[0]; sr[4]=sph[1]; sr[5]=sph[2]; sr[6]=cmf;
  float* vr = ws + WS_NDV + (size_t)n * 9;
  vr[0]=fx; vr[1]=fy; vr[2]=fz; vr[3]=kx; vr[4]=ky; vr[5]=kz; vr[6]=sx; vr[7]=sy; vr[8]=sz;
}

// ---------------- Kernel D1: vh = wh^T * node_v ; vn -> s_in[7..262] ----------------
__global__ __launch_bounds__(256) void kgvp_pre(float* __restrict__ ws,
                                                const float* __restrict__ wh,
                                                float* __restrict__ avh) {
  int n = blockIdx.x, h = threadIdx.x;
  const float* v = ws + WS_NDV + (size_t)n * 9;
  float w0 = wh[h], w1 = wh[256+h], w2 = wh[512+h];
  float vh0 = v[0]*w0 + v[3]*w1 + v[6]*w2;
  float vh1 = v[1]*w0 + v[4]*w1 + v[7]*w2;
  float vh2 = v[2]*w0 + v[5]*w1 + v[8]*w2;
  avh[(size_t)0*Nn*256 + (size_t)n*256 + h] = vh0;
  avh[(size_t)1*Nn*256 + (size_t)n*256 + h] = vh1;
  avh[(size_t)2*Nn*256 + (size_t)n*256 + h] = vh2;
  ws[WS_SIN + (size_t)n*SK + 7 + h] = sqrtf(fmaxf(vh0*vh0 + vh1*vh1 + vh2*vh2, 1e-8f));
}

// ---- block-wide scan over 256 bins + cutoff-bin search (helper for ktopk) ----
__device__ __forceinline__ void scan_cut(unsigned cnt, int tid, unsigned target,
                                         unsigned* wsum, int* cut_s, unsigned* nb_s) {
  int lane = tid & 63, wid = tid >> 6;
  unsigned v = cnt;
  #pragma unroll
  for (int off = 1; off < 64; off <<= 1) {
    unsigned o = __shfl_up(v, off);
    if (lane >= off) v += o;
  }
  if (lane == 63) wsum[wid] = v;
  __syncthreads();
  unsigned offs = 0;
  for (int w = 0; w < wid; ++w) offs += wsum[w];
  unsigned incl = v + offs;
  unsigned below = incl - cnt;
  if (incl >= target && below < target) { *cut_s = tid; *nb_s = below; }
  __syncthreads();
}

// ---------------- Kernel B: exact kNN top-30 via two-level radix select ----------
// u64 key = (float_bits(D_adjust)<<32)|j — order-preserving (adj>=0), unique,
// lowest-index tie-break. Radix-select on key bits [63:48], compact, rank-by-count.
__global__ __launch_bounds__(256) void ktopk(const float* __restrict__ coords,
                                             const int* __restrict__ resid,
                                             const unsigned char* __restrict__ pmask,
                                             float* __restrict__ ws) {
  __shared__ float xs[Lc*3];
  __shared__ int   res[Lc];
  __shared__ unsigned cmw[Lc/32];
  __shared__ unsigned rmw[Lc/32];
  __shared__ unsigned hist[256];
  __shared__ unsigned wsum[4];
  __shared__ int      cut_s;
  __shared__ unsigned nb_s;
  __shared__ unsigned long long cbuf[512];
  __shared__ unsigned ccnt;
  int row = blockIdx.x;
  int b = row >> 11, i = row & (Lc-1);
  int tid = threadIdx.x;
  if (tid < Lc/32) { cmw[tid] = 0; rmw[tid] = 0; }
  hist[tid] = 0;
  if (tid == 0) ccnt = 0;
  __syncthreads();
  const float* Xb = coords + (size_t)b * Lc * 9;
  for (int j = tid; j < Lc; j += 256) {
    xs[j*3+0] = Xb[j*9+3]; xs[j*3+1] = Xb[j*9+4]; xs[j*3+2] = Xb[j*9+5];
    if (ws[WS_CMF + b*Lc + j] != 0.f) atomicOr(&cmw[j>>5], 1u << (j&31));
    if (!pmask[b*Lc + j])             atomicOr(&rmw[j>>5], 1u << (j&31));
    res[j] = resid[b*Lc + j];
  }
  __syncthreads();
  float xi0 = xs[i*3+0], xi1 = xs[i*3+1], xi2 = xs[i*3+2];
  float cmi = (cmw[i>>5] >> (i&31)) & 1 ? 1.f : 0.f;
  float rmi = (rmw[i>>5] >> (i&31)) & 1 ? 1.f : 0.f;
  int ri = res[i];
  unsigned long long key[8];
  #pragma unroll
  for (int m = 0; m < 8; ++m) {
    int j = tid + 256*m;
    float cmj = (cmw[j>>5] >> (j&31)) & 1 ? 1.f : 0.f;
    float rmj = (rmw[j>>5] >> (j&31)) & 1 ? 1.f : 0.f;
    float dx = __fsub_rn(xi0, xs[j*3+0]);
    float dy = __fsub_rn(xi1, xs[j*3+1]);
    float dz = __fsub_rn(xi2, xs[j*3+2]);
    float ss = __fadd_rn(__fadd_rn(__fmul_rn(dx,dx), __fmul_rn(dy,dy)), __fmul_rn(dz,dz));
    float dist = __fsqrt_rn(__fadd_rn(ss, 1e-8f));
    float cm2 = __fmul_rn(cmi, cmj);
    float D = __fmul_rn(cm2, dist);
    int ad = ri - res[j]; ad = ad < 0 ? -ad : ad;
    float covm = (ad <= 3) ? 0.f : 1.f;                 // (1 - cov)
    float dseq = (float)(i >= j ? i - j : j - i);
    float t1 = __fmul_rn(__fsub_rn(1.f, cm2), __fadd_rn(1e8f, __fmul_rn(dseq, 1e6f)));
    float rm2 = __fmul_rn(rmi, rmj);
    float t2 = __fmul_rn(__fsub_rn(1.f, rm2), 1e10f);
    float adj = __fadd_rn(__fadd_rn(__fmul_rn(D, covm), t1), t2);
    key[m] = ((unsigned long long)__float_as_uint(adj) << 32) | (unsigned int)j;
  }
  // level-1 histogram: key bits [63:56]
  #pragma unroll
  for (int m = 0; m < 8; ++m) atomicAdd(&hist[(unsigned)(key[m] >> 56)], 1u);
  __syncthreads();
  scan_cut(hist[tid], tid, Kc, wsum, &cut_s, &nb_s);
  int c1 = cut_s; unsigned nb1 = nb_s;
  __syncthreads();
  // level-2 histogram: bits [55:48] within bin c1
  hist[tid] = 0;
  __syncthreads();
  #pragma unroll
  for (int m = 0; m < 8; ++m)
    if ((int)(key[m] >> 56) == c1) atomicAdd(&hist[(unsigned)(key[m] >> 48) & 0xFF], 1u);
  __syncthreads();
  scan_cut(hist[tid], tid, Kc - nb1, wsum, &cut_s, &nb_s);
  unsigned cut16 = ((unsigned)c1 << 8) | (unsigned)cut_s;
  __syncthreads();
  // compact all keys with hi16 <= cut16 (count >= Kc by construction)
  #pragma unroll
  for (int m = 0; m < 8; ++m) {
    if ((unsigned)(key[m] >> 48) <= cut16) {
      unsigned p = atomicAdd(&ccnt, 1u);
      if (p < 512) cbuf[p] = key[m];
    }
  }
  __syncthreads();
  int M = ccnt < 512u ? (int)ccnt : 512;
  int* eix = (int*)(ws + WS_EIX);
  for (int idx = tid; idx < M; idx += 256) {
    unsigned long long k0 = cbuf[idx];
    int rank = 0;
    for (int s2 = 0; s2 < M; ++s2) rank += (cbuf[s2] < k0) ? 1 : 0;
    if (rank < Kc) {
      int j = (int)(k0 & 0xffffffffULL);
      float cmj = (cmw[j>>5] >> (j&31)) & 1 ? 1.f : 0.f;
      float dx = __fsub_rn(xi0, xs[j*3+0]);
      float dy = __fsub_rn(xi1, xs[j*3+1]);
      float dz = __fsub_rn(xi2, xs[j*3+2]);
      float ss = __fadd_rn(__fadd_rn(__fmul_rn(dx,dx), __fmul_rn(dy,dy)), __fmul_rn(dz,dz));
      float dist = __fsqrt_rn(__fadd_rn(ss, 1e-8f));
      float D = __fmul_rn(__fmul_rn(cmi, cmj), dist);
      eix[(size_t)row*Kc + rank] = j;
      ws[WS_EDS + (size_t)row*Kc + rank] = D;
    }
  }
}

// ---------------- Kernel D2: S GEMM (8192x263)@(263x1024)+bias -> ns region ----------------
__global__ __launch_bounds__(256) void kgemm_s(const float* __restrict__ ws,
                                               const float* __restrict__ wsw,
                                               const float* __restrict__ wsb,
                                               float* __restrict__ out) {
  __shared__ float A[16][SK+1];
  int tid = threadIdx.x;
  int row0 = blockIdx.x * 16;
  for (int r = 0; r < 16; ++r)
    for (int k = tid; k < SK; k += 256)
      A[r][k] = ws[WS_SIN + (size_t)(row0+r)*SK + k];
  __syncthreads();
  float acc[16][4];
  #pragma unroll
  for (int r = 0; r < 16; ++r) { acc[r][0]=0.f; acc[r][1]=0.f; acc[r][2]=0.f; acc[r][3]=0.f; }
  for (int k = 0; k < SK; ++k) {
    float b0 = wsw[(size_t)k*NSc + tid];
    float b1 = wsw[(size_t)k*NSc + tid + 256];
    float b2 = wsw[(size_t)k*NSc + tid + 512];
    float b3 = wsw[(size_t)k*NSc + tid + 768];
    #pragma unroll
    for (int r = 0; r < 16; ++r) {
      float a = A[r][k];
      acc[r][0] = fmaf(a, b0, acc[r][0]);
      acc[r][1] = fmaf(a, b1, acc[r][1]);
      acc[r][2] = fmaf(a, b2, acc[r][2]);
      acc[r][3] = fmaf(a, b3, acc[r][3]);
    }
  }
  float bb0 = wsb[tid], bb1 = wsb[tid+256], bb2 = wsb[tid+512], bb3 = wsb[tid+768];
  for (int r = 0; r < 16; ++r) {
    size_t o = OUT_NS + (size_t)(row0+r)*NSc + tid;
    out[o]     = acc[r][0] + bb0;
    out[o+256] = acc[r][1] + bb1;
    out[o+512] = acc[r][2] + bb2;
    out[o+768] = acc[r][3] + bb3;
  }
}

// ---------------- Kernel D3: V GEMM per d: (8192x256)@(256x256) -> nv region ----------------
__global__ __launch_bounds__(256) void kgemm_v(const float* __restrict__ avh,
                                               const float* __restrict__ wv,
                                               float* __restrict__ out) {
  int d = blockIdx.y;
  int row0 = blockIdx.x * 16;
  int tid = threadIdx.x;
  __shared__ float A[16][257];
  const float* Ad = avh + (size_t)d * Nn * 256;
  for (int r = 0; r < 16; ++r) A[r][tid] = Ad[(size_t)(row0+r)*256 + tid];
  __syncthreads();
  float acc[16];
  #pragma unroll
  for (int r = 0; r < 16; ++r) acc[r] = 0.f;
  for (int k = 0; k < 256; ++k) {
    float bb = wv[(size_t)k*256 + tid];
    #pragma unroll
    for (int r = 0; r < 16; ++r) acc[r] = fmaf(A[r][k], bb, acc[r]);
  }
  for (int r = 0; r < 16; ++r)
    out[OUT_NV + (size_t)(row0+r)*768 + (size_t)tid*3 + d] = acc[r];
}

// ---------------- Kernel C: edge features + edge GVP + edge LN + ei ----------------
// E_mean is provably dead: edges with E_cmf=0 are exactly the invalid ones whose
// es/ev get where(valid,...,0) — so invalid lanes write exact zeros and exit.
__global__ __launch_bounds__(256) void kedge(const float* __restrict__ coords,
    const int* __restrict__ resid,
    const float* __restrict__ ewh, const float* __restrict__ eww,
    const float* __restrict__ ewb, const float* __restrict__ ewv,
    const float* __restrict__ elg, const float* __restrict__ elb,
    const float* __restrict__ ws, float* __restrict__ out) {
  __shared__ float w[35*32];
  __shared__ float wb[32], g[32], bb[32];
  int tid = threadIdx.x;
  for (int t = tid; t < 35*32; t += 256) w[t] = eww[t];
  if (tid < 32) { wb[tid] = ewb[tid]; g[tid] = elg[tid]; bb[tid] = elb[tid]; }
  __syncthreads();
  int e = blockIdx.x * 256 + tid;
  if (e >= NEc) return;
  int b = e / (Lc*Kc);
  int rem = e - b*(Lc*Kc);
  int i = rem / Kc;
  int row = b*Lc + i;
  const int* eix = (const int*)(ws + WS_EIX);
  int j = eix[e];
  float Dn = ws[WS_EDS + e];
  bool valid = (Dn < 5e7f) && (Dn < 5e9f);
  if (!valid) {
    #pragma unroll
    for (int c = 0; c < 32; ++c) out[OUT_ES + (size_t)e*32 + c] = 0.f;
    out[OUT_EV + (size_t)e*3 + 0] = 0.f;
    out[OUT_EV + (size_t)e*3 + 1] = 0.f;
    out[OUT_EV + (size_t)e*3 + 2] = 0.f;
    out[OUT_EI + e]       = -1.f;
    out[OUT_EI + NEc + e] = -1.f;
    return;
  }
  int dcl = resid[row] - resid[b*Lc + j];
  dcl = dcl < -32 ? -32 : (dcl > 32 ? 32 : dcl);
  float dpos = (float)dcl;
  float s[35];
  #pragma unroll
  for (int m = 0; m < 16; ++m) {
    float c = (20.f/15.f) * (float)m;
    float z = (Dn - c) * 0.8f;
    s[m] = expf(-z*z);
  }
  #pragma unroll
  for (int m = 0; m < 8; ++m) {
    float fr = expf((float)(2*m) * (-0.57564627324851148f));
    float ang = dpos * fr;
    s[16+m] = cosf(ang);
    s[24+m] = sinf(ang);
  }
  float csf = ws[WS_CMF + row];
  float cdf = ws[WS_CMF + b*Lc + j];
  s[32] = 1.f - csf; s[33] = 1.f - cdf;
  const float* Xb = coords + (size_t)b*Lc*9;
  float vx = Xb[i*9+3] - Xb[j*9+3];
  float vy = Xb[i*9+4] - Xb[j*9+4];
  float vz = Xb[i*9+5] - Xb[j*9+5];
  float ss2 = vx*vx + vy*vy + vz*vz;
  float inv = 1.f / sqrtf(ss2 + 1e-8f);
  float e0 = vx*inv, e1 = vy*inv, e2 = vz*inv;
  if (!isfinite(e0)) e0 = 0.f;
  if (!isfinite(e1)) e1 = 0.f;
  if (!isfinite(e2)) e2 = 0.f;
  float wh00 = ewh[0], wv00 = ewv[0];
  float vh0 = e0*wh00, vh1 = e1*wh00, vh2 = e2*wh00;
  s[34] = sqrtf(fmaxf(vh0*vh0 + vh1*vh1 + vh2*vh2, 1e-8f));
  float o[32]; float sm = 0.f;
  #pragma unroll
  for (int c = 0; c < 32; ++c) {
    float a = wb[c];
    #pragma unroll
    for (int q = 0; q < 35; ++q) a = fmaf(s[q], w[q*32 + c], a);
    o[c] = a; sm += a;
  }
  float mu = sm * (1.f/32.f);
  float sq = 0.f;
  #pragma unroll
  for (int c = 0; c < 32; ++c) { float dd = o[c]-mu; sq += dd*dd; }
  float isd = 1.f / sqrtf(sq*(1.f/32.f) + 1e-4f);
  float vo0 = vh0*wv00, vo1 = vh1*wv00, vo2 = vh2*wv00;
  float vn2 = fmaxf(vo0*vo0 + vo1*vo1 + vo2*vo2, 1e-8f);
  float ivn = 1.f / sqrtf(vn2);
  #pragma unroll
  for (int c = 0; c < 32; ++c)
    out[OUT_ES + (size_t)e*32 + c] = (o[c]-mu)*isd*g[c] + bb[c];
  out[OUT_EV + (size_t)e*3 + 0] = vo0*ivn;
  out[OUT_EV + (size_t)e*3 + 1] = vo1*ivn;
  out[OUT_EV + (size_t)e*3 + 2] = vo2*ivn;
  out[OUT_EI + e]       = (float)row;
  out[OUT_EI + NEc + e] = (float)(b*Lc + j);
}

// ---------------- Kernel D4: node LayerNorm + confidence RBF term ----------------
__global__ __launch_bounds__(256) void kln_node(const float* __restrict__ conf,
    const float* __restrict__ cw, const float* __restrict__ cb,
    const float* __restrict__ lg, const float* __restrict__ lb,
    float* __restrict__ out) {
  int n = blockIdx.x, tid = threadIdx.x;
  size_t base = OUT_NS + (size_t)n*NSc;
  float x0 = out[base + tid];
  float x1 = out[base + tid + 256];
  float x2 = out[base + tid + 512];
  float x3 = out[base + tid + 768];
  float sm = x0+x1+x2+x3;
  float sq = x0*x0+x1*x1+x2*x2+x3*x3;
  int lane = tid & 63, wid = tid >> 6;
  #pragma unroll
  for (int off = 32; off > 0; off >>= 1) { sm += __shfl_down(sm, off); sq += __shfl_down(sq, off); }
  __shared__ float rs[4], rq[4];
  if (lane == 0) { rs[wid] = sm; rq[wid] = sq; }
  __syncthreads();
  sm = rs[0]+rs[1]+rs[2]+rs[3];
  sq = rq[0]+rq[1]+rq[2]+rq[3];
  float mu = sm * (1.f/1024.f);
  float var = fmaxf(sq * (1.f/1024.f) - mu*mu, 0.f);
  float isd = 1.f / sqrtf(var + 1e-4f);
  float cf = conf[n];
  float rb[16];
  #pragma unroll
  for (int m = 0; m < 16; ++m) {
    float z = (cf - (float)m*(1.f/15.f)) * 16.f;
    rb[m] = expf(-z*z);
  }
  float xs_[4] = {x0, x1, x2, x3};
  #pragma unroll
  for (int q = 0; q < 4; ++q) {
    int c = tid + q*256;
    float t = cb[c];
    #pragma unroll
    for (int m = 0; m < 16; ++m) t = fmaf(rb[m], cw[m*1024 + c], t);
    out[base + c] = (xs_[q]-mu)*isd*lg[c] + lb[c] + t;
  }
}

// ---------------- Kernel D5: node vector norm epilogue ----------------
__global__ __launch_bounds__(256) void kvnorm(float* __restrict__ out) {
  int n = blockIdx.x, tid = threadIdx.x;
  size_t base = OUT_NV + (size_t)n*768;
  float v0 = out[base + tid*3 + 0];
  float v1 = out[base + tid*3 + 1];
  float v2 = out[base + tid*3 + 2];
  float vn2 = fmaxf(v0*v0 + v1*v1 + v2*v2, 1e-8f);
  int lane = tid & 63, wid = tid >> 6;
  float sm = vn2;
  #pragma unroll
  for (int off = 32; off > 0; off >>= 1) sm += __shfl_down(sm, off);
  __shared__ float rs[4];
  if (lane == 0) rs[wid] = sm;
  __syncthreads();
  sm = rs[0]+rs[1]+rs[2]+rs[3];
  float isd = 1.f / sqrtf(sm * (1.f/256.f));
  out[base + tid*3 + 0] = v0*isd;
  out[base + tid*3 + 1] = v1*isd;
  out[base + tid*3 + 2] = v2*isd;
}

extern "C" void kernel_launch(void* const* d_in, const int* in_sizes, int n_in,
                              void* d_out, int out_size, void* d_ws, size_t ws_size,
                              hipStream_t stream) {
  const float* coords         = (const float*)d_in[0];
  const unsigned char* cmask  = (const unsigned char*)d_in[1];
  const int* resid            = (const int*)d_in[2];
  const unsigned char* pmask  = (const unsigned char*)d_in[3];
  const float* conf           = (const float*)d_in[4];
  const float* nwh            = (const float*)d_in[5];
  const float* nww            = (const float*)d_in[6];
  const float* nwb            = (const float*)d_in[7];
  const float* nwv            = (const float*)d_in[8];
  const float* nlg            = (const float*)d_in[9];
  const float* nlb            = (const float*)d_in[10];
  const float* ewh            = (const float*)d_in[11];
  const float* eww            = (const float*)d_in[12];
  const float* ewb            = (const float*)d_in[13];
  const float* ewv            = (const float*)d_in[14];
  const float* elg            = (const float*)d_in[15];
  const float* elb            = (const float*)d_in[16];
  const float* cw             = (const float*)d_in[17];
  const float* cb             = (const float*)d_in[18];
  float* out = (float*)d_out;
  float* ws  = (float*)d_ws;
  float* avh = out + OUT_ES;   // stage vh in es output region; consumed before kedge writes es

  kmask<<<1, 1024, 0, stream>>>(cmask, ws);
  knode_geom<<<(Nn+255)/256, 256, 0, stream>>>(coords, ws);
  kgvp_pre<<<Nn, 256, 0, stream>>>(ws, nwh, avh);
  ktopk<<<Nn, 256, 0, stream>>>(coords, resid, pmask, ws);
  kgemm_s<<<Nn/16, 256, 0, stream>>>(ws, nww, nwb, out);
  kgemm_v<<<dim3(Nn/16, 3), 256, 0, stream>>>(avh, nwv, out);
  kedge<<<NEc/256, 256, 0, stream>>>(coords, resid, ewh, eww, ewb, ewv, elg, elb, ws, out);
  kln_node<<<Nn, 256, 0, stream>>>(conf, cw, cb, nlg, nlb, out);
  kvnorm<<<Nn, 256, 0, stream>>>(out);
}

// Round 6
// 554.564 us; speedup vs baseline: 1.7302x; 1.0927x over previous
//
#include <hip/hip_runtime.h>
#include <math.h>

// ---- problem constants ----
constexpr int Bc = 4, Lc = 2048, Kc = 30;
constexpr int Nn = Bc * Lc;            // 8192 nodes
constexpr int NSc = 1024, NVc = 256;
constexpr int NEc = Nn * Kc;           // 245760 edges
constexpr int SK = 263;                // 7 + 256 scalar GVP input dim

// ---- d_out float offsets (outputs concatenated flat in return order) ----
constexpr size_t OUT_NS = 0;                                  // (8192,1024)
constexpr size_t OUT_NV = (size_t)Nn * NSc;                   // (8192,256,3)
constexpr size_t OUT_ES = OUT_NV + (size_t)Nn * NVc * 3;      // (245760,32)
constexpr size_t OUT_EV = OUT_ES + (size_t)NEc * 32;          // (245760,1,3)
constexpr size_t OUT_EI = OUT_EV + (size_t)NEc * 3;           // (2,245760) as float

// ---- workspace float offsets ----
constexpr size_t WS_SIN = 0;                                  // (8192,263) s_in
constexpr size_t WS_NDV = WS_SIN + (size_t)Nn * SK;           // (8192,9) node_v
constexpr size_t WS_EIX = WS_NDV + (size_t)Nn * 9;            // (245760) int E_idx
constexpr size_t WS_EDS = WS_EIX + (size_t)NEc;               // (245760) E_dist
constexpr size_t WS_CMF = WS_EDS + (size_t)NEc;               // (8192) canonical coord_mask float

__device__ __forceinline__ void norml3(float& x, float& y, float& z) {
  float ss = x*x + y*y + z*z;
  float inv = 1.0f / sqrtf(ss + 1e-8f);
  x *= inv; y *= inv; z *= inv;
}

// ---------------- Kernel M: canonicalize coord_mask (bytes-vs-int32 autodetect) ----
__global__ __launch_bounds__(1024) void kmask(const unsigned char* __restrict__ cm,
                                              float* __restrict__ ws) {
  __shared__ int flag;
  if (threadIdx.x == 0) flag = 0;
  __syncthreads();
  int any = 0;
  for (int p = threadIdx.x; p < Nn; p += 1024)
    if (p & 3) any |= cm[p];
  if (any) atomicOr(&flag, 1);
  __syncthreads();
  bool bytefmt = (flag != 0);
  float* cmf = ws + WS_CMF;
  for (int n = threadIdx.x; n < Nn; n += 1024) {
    unsigned char v = bytefmt ? cm[n] : cm[4*n];  // LE low byte of int32 0/1
    cmf[n] = v ? 1.f : 0.f;
  }
}

// ---------------- Kernel A: per-node geometric features ----------------
__global__ __launch_bounds__(256) void knode_geom(const float* __restrict__ coords,
                                                  float* __restrict__ ws) {
  int n = blockIdx.x * 256 + threadIdx.x;
  if (n >= Nn) return;
  int b = n / Lc, l = n % Lc;
  const float* Xb = coords + (size_t)b * Lc * 9;
  float ax[7][3];
  #pragma unroll
  for (int m = 0; m < 7; ++m) {
    int t = 3*l + m - 2;
    if (t >= 0 && t < 3*Lc) { ax[m][0]=Xb[t*3+0]; ax[m][1]=Xb[t*3+1]; ax[m][2]=Xb[t*3+2]; }
    else { ax[m][0]=0.f; ax[m][1]=0.f; ax[m][2]=0.f; }
  }
  float U[5][3];
  #pragma unroll
  for (int mi = 0; mi < 5; ++mi) {
    int t = 3*l - 1 + mi;
    if (t >= 0 && t <= 3*Lc - 2) {
      float x = ax[mi+2][0]-ax[mi+1][0], y = ax[mi+2][1]-ax[mi+1][1], z = ax[mi+2][2]-ax[mi+1][2];
      norml3(x,y,z);
      U[mi][0]=x; U[mi][1]=y; U[mi][2]=z;
    } else { U[mi][0]=0.f; U[mi][1]=0.f; U[mi][2]=0.f; }
  }
  float cph[3], sph[3];
  #pragma unroll
  for (int a = 0; a < 3; ++a) {
    int t = 3*l + a - 1;
    if (t < 0 || t > 3*Lc - 4) { cph[a] = 1.f; sph[a] = 0.f; continue; }
    const float *u2 = U[a], *u1 = U[a+1], *u0 = U[a+2];
    float n2x = u2[1]*u1[2]-u2[2]*u1[1], n2y = u2[2]*u1[0]-u2[0]*u1[2], n2z = u2[0]*u1[1]-u2[1]*u1[0];
    norml3(n2x,n2y,n2z);
    float n1x = u1[1]*u0[2]-u1[2]*u0[1], n1y = u1[2]*u0[0]-u1[0]*u0[2], n1z = u1[0]*u0[1]-u1[1]*u0[0];
    norml3(n1x,n1y,n1z);
    float cd = n2x*n1x + n2y*n1y + n2z*n1z;
    cd = fminf(fmaxf(cd, -1.f + 1e-7f), 1.f - 1e-7f);
    float dt = u2[0]*n1x + u2[1]*n1y + u2[2]*n1z;
    float sg = (dt > 0.f) ? 1.f : ((dt < 0.f) ? -1.f : 0.f);
    float D = sg * acosf(cd);
    cph[a] = cosf(D); sph[a] = sinf(D);
  }
  float fx=0.f,fy=0.f,fz=0.f, kx=0.f,ky=0.f,kz=0.f;
  if (l < Lc-1) { fx=ax[6][0]-ax[3][0]; fy=ax[6][1]-ax[3][1]; fz=ax[6][2]-ax[3][2]; norml3(fx,fy,fz); }
  if (l > 0)    { kx=ax[0][0]-ax[3][0]; ky=ax[0][1]-ax[3][1]; kz=ax[0][2]-ax[3][2]; norml3(kx,ky,kz); }
  float cx=ax[4][0]-ax[3][0], cy=ax[4][1]-ax[3][1], cz=ax[4][2]-ax[3][2]; norml3(cx,cy,cz);
  float nx=ax[2][0]-ax[3][0], ny=ax[2][1]-ax[3][1], nz=ax[2][2]-ax[3][2]; norml3(nx,ny,nz);
  float bix=cx+nx, biy=cy+ny, biz=cz+nz; norml3(bix,biy,biz);
  float px=cy*nz-cz*ny, py=cz*nx-cx*nz, pz=cx*ny-cy*nx; norml3(px,py,pz);
  const float c1 = 0.57735026f, c2 = 0.81649658f;
  float sx = -bix*c1 - px*c2, sy = -biy*c1 - py*c2, sz = -biz*c1 - pz*c2;

  float cmf = ws[WS_CMF + n];
  float* sr = ws + WS_SIN + (size_t)n * SK;
  sr[0]=cph[0]; sr[1]=cph[1]; sr[2]=cph[2]; sr[3]=sph[0]; sr[4]=sph[1]; sr[5]=sph[2]; sr[6]=cmf;
  float* vr = ws + WS_NDV + (size_t)n * 9;
  vr[0]=fx; vr[1]=fy; vr[2]=fz; vr[3]=kx; vr[4]=ky; vr[5]=kz; vr[6]=sx; vr[7]=sy; vr[8]=sz;
}

// ---------------- Kernel D1: vh = wh^T * node_v ; vn -> s_in[7..262] ----------------
__global__ __launch_bounds__(256) void kgvp_pre(float* __restrict__ ws,
                                                const float* __restrict__ wh,
                                                float* __restrict__ avh) {
  int n = blockIdx.x, h = threadIdx.x;
  const float* v = ws + WS_NDV + (size_t)n * 9;
  float w0 = wh[h], w1 = wh[256+h], w2 = wh[512+h];
  float vh0 = v[0]*w0 + v[3]*w1 + v[6]*w2;
  float vh1 = v[1]*w0 + v[4]*w1 + v[7]*w2;
  float vh2 = v[2]*w0 + v[5]*w1 + v[8]*w2;
  avh[(size_t)0*Nn*256 + (size_t)n*256 + h] = vh0;
  avh[(size_t)1*Nn*256 + (size_t)n*256 + h] = vh1;
  avh[(size_t)2*Nn*256 + (size_t)n*256 + h] = vh2;
  ws[WS_SIN + (size_t)n*SK + 7 + h] = sqrtf(fmaxf(vh0*vh0 + vh1*vh1 + vh2*vh2, 1e-8f));
}

// ---------------- Kernel B: wave-autonomous exact top-30 radix select ----------
// One wave per row, 16 rows/block over one staged tile. Cross-lane coordination
// uses ballot/shfl/popc (registers) exclusively; LDS is used only for the 256-bin
// histogram (atomics fenced by wave_barrier) and the compacted candidate buffer
// (deterministic ballot-prefix positions, no counters). u64 key =
// (f32bits(adj)<<32)|j — exact order, lowest-index ties.
__global__ __launch_bounds__(256) void ktopk(const float* __restrict__ coords,
                                             const int* __restrict__ resid,
                                             const unsigned char* __restrict__ pmask,
                                             float* __restrict__ ws) {
  __shared__ float xsx[Lc], xsy[Lc], xsz[Lc];
  __shared__ int   res[Lc];
  __shared__ unsigned cmw[Lc/32], rmw[Lc/32];
  __shared__ unsigned hist[4][256];
  __shared__ unsigned long long cbuf[4][256];
  int tid = threadIdx.x, lane = tid & 63, wid = tid >> 6;
  int row0 = blockIdx.x * 16;
  int b = row0 >> 11;
  int i0 = row0 & (Lc - 1);
  const float* Xb = coords + (size_t)b * Lc * 9;
  for (int it = 0; it < Lc/256; ++it) {
    int j = tid + 256*it;
    xsx[j] = Xb[j*9+3]; xsy[j] = Xb[j*9+4]; xsz[j] = Xb[j*9+5];
    res[j] = resid[b*Lc + j];
    unsigned long long mcm = __ballot(ws[WS_CMF + b*Lc + j] != 0.f);
    unsigned long long mrm = __ballot(pmask[b*Lc + j] == 0);
    if (lane == 0) {
      int w0 = j >> 5;                      // j%64==0 at lane 0
      cmw[w0] = (unsigned)mcm; cmw[w0+1] = (unsigned)(mcm >> 32);
      rmw[w0] = (unsigned)mrm; rmw[w0+1] = (unsigned)(mrm >> 32);
    }
  }
  __syncthreads();
  int* eix = (int*)(ws + WS_EIX);
  unsigned long long lmask_lt = (1ULL << lane) - 1ULL;
  for (int rr = 0; rr < 4; ++rr) {
    int i = i0 + wid*4 + rr;
    int row = row0 + wid*4 + rr;
    float xi0 = xsx[i], xi1 = xsy[i], xi2 = xsz[i];
    float cmi = ((cmw[i>>5] >> (i&31)) & 1) ? 1.f : 0.f;
    float rmi = ((rmw[i>>5] >> (i&31)) & 1) ? 1.f : 0.f;
    int ri = res[i];
    unsigned long long key[32];
    #pragma unroll
    for (int m = 0; m < 32; ++m) {
      int j = lane + 64*m;
      float cmj = ((cmw[j>>5] >> (j&31)) & 1) ? 1.f : 0.f;
      float rmj = ((rmw[j>>5] >> (j&31)) & 1) ? 1.f : 0.f;
      float dx = __fsub_rn(xi0, xsx[j]);
      float dy = __fsub_rn(xi1, xsy[j]);
      float dz = __fsub_rn(xi2, xsz[j]);
      float ss = __fadd_rn(__fadd_rn(__fmul_rn(dx,dx), __fmul_rn(dy,dy)), __fmul_rn(dz,dz));
      float dist = __fsqrt_rn(__fadd_rn(ss, 1e-8f));
      float cm2 = __fmul_rn(cmi, cmj);
      float D = __fmul_rn(cm2, dist);
      int ad = ri - res[j]; ad = ad < 0 ? -ad : ad;
      float covm = (ad <= 3) ? 0.f : 1.f;
      float dseq = (float)(i >= j ? i - j : j - i);
      float t1 = __fmul_rn(__fsub_rn(1.f, cm2), __fadd_rn(1e8f, __fmul_rn(dseq, 1e6f)));
      float rm2 = __fmul_rn(rmi, rmj);
      float t2 = __fmul_rn(__fsub_rn(1.f, rm2), 1e10f);
      float adj = __fadd_rn(__fadd_rn(__fmul_rn(D, covm), t1), t2);
      key[m] = ((unsigned long long)__float_as_uint(adj) << 32) | (unsigned int)j;
    }
    unsigned cut16;
    {
      // ---- level-1: 256-bin histogram on key bits [63:56] ----
      hist[wid][lane*4+0] = 0; hist[wid][lane*4+1] = 0;
      hist[wid][lane*4+2] = 0; hist[wid][lane*4+3] = 0;
      __builtin_amdgcn_wave_barrier();
      #pragma unroll
      for (int m = 0; m < 32; ++m) atomicAdd(&hist[wid][(unsigned)(key[m] >> 56)], 1u);
      __builtin_amdgcn_wave_barrier();
      unsigned h0 = hist[wid][lane*4+0], h1 = hist[wid][lane*4+1];
      unsigned h2 = hist[wid][lane*4+2], h3 = hist[wid][lane*4+3];
      unsigned s = h0+h1+h2+h3;
      unsigned v = s;
      #pragma unroll
      for (int off = 1; off < 64; off <<= 1) { unsigned o = __shfl_up(v, off); if (lane >= off) v += o; }
      unsigned excl = v - s;
      unsigned target = Kc;
      unsigned inc0 = excl+h0, inc1 = inc0+h1, inc2 = inc1+h2, inc3 = inc2+h3;
      bool cross = (inc3 >= target) && (excl < target);
      unsigned cb, nb;
      if      (inc0 >= target) { cb = 0; nb = excl; }
      else if (inc1 >= target) { cb = 1; nb = inc0; }
      else if (inc2 >= target) { cb = 2; nb = inc1; }
      else                     { cb = 3; nb = inc2; }
      int src = __ffsll((long long)__ballot(cross)) - 1;
      if (src < 0) src = 0;
      unsigned c1  = __shfl((unsigned)(lane*4) + cb, src);
      unsigned nb1 = __shfl(nb, src);
      // ---- level-2: histogram on bits [55:48] within bin c1 ----
      hist[wid][lane*4+0] = 0; hist[wid][lane*4+1] = 0;
      hist[wid][lane*4+2] = 0; hist[wid][lane*4+3] = 0;
      __builtin_amdgcn_wave_barrier();
      #pragma unroll
      for (int m = 0; m < 32; ++m)
        if ((unsigned)(key[m] >> 56) == c1) atomicAdd(&hist[wid][(unsigned)(key[m] >> 48) & 0xFF], 1u);
      __builtin_amdgcn_wave_barrier();
      h0 = hist[wid][lane*4+0]; h1 = hist[wid][lane*4+1];
      h2 = hist[wid][lane*4+2]; h3 = hist[wid][lane*4+3];
      s = h0+h1+h2+h3;
      v = s;
      #pragma unroll
      for (int off = 1; off < 64; off <<= 1) { unsigned o = __shfl_up(v, off); if (lane >= off) v += o; }
      excl = v - s;
      target = Kc - nb1;
      inc0 = excl+h0; inc1 = inc0+h1; inc2 = inc1+h2; inc3 = inc2+h3;
      cross = (inc3 >= target) && (excl < target);
      if      (inc0 >= target) cb = 0;
      else if (inc1 >= target) cb = 1;
      else if (inc2 >= target) cb = 2;
      else                     cb = 3;
      src = __ffsll((long long)__ballot(cross)) - 1;
      if (src < 0) src = 0;
      cut16 = __shfl((c1 << 8) | ((unsigned)(lane*4) + cb), src);
    }
    // ---- compact keys with hi16 <= cut16 via deterministic ballot prefix ----
    unsigned base = 0;
    #pragma unroll
    for (int m = 0; m < 32; ++m) {
      bool pred = ((unsigned)(key[m] >> 48) <= cut16);
      unsigned long long bal = __ballot(pred);
      if (pred) {
        unsigned pos = base + (unsigned)__popcll(bal & lmask_lt);
        if (pos < 256u) cbuf[wid][pos] = key[m];
      }
      base += (unsigned)__popcll(bal);
    }
    unsigned M = base < 256u ? base : 256u;
    __builtin_amdgcn_wave_barrier();
    // ---- rank by counting among compacted candidates, emit top-Kc ----
    for (unsigned idx = (unsigned)lane; idx < M; idx += 64u) {
      unsigned long long k0 = cbuf[wid][idx];
      int rank = 0;
      for (unsigned t = 0; t < M; ++t) rank += (cbuf[wid][t] < k0) ? 1 : 0;
      if (rank < Kc) {
        int j = (int)(k0 & 0xffffffffULL);
        float cmj = ((cmw[j>>5] >> (j&31)) & 1) ? 1.f : 0.f;
        float dx = __fsub_rn(xi0, xsx[j]);
        float dy = __fsub_rn(xi1, xsy[j]);
        float dz = __fsub_rn(xi2, xsz[j]);
        float ss2 = __fadd_rn(__fadd_rn(__fmul_rn(dx,dx), __fmul_rn(dy,dy)), __fmul_rn(dz,dz));
        float dist = __fsqrt_rn(__fadd_rn(ss2, 1e-8f));
        float D = __fmul_rn(__fmul_rn(cmi, cmj), dist);
        eix[(size_t)row*Kc + rank] = j;
        ws[WS_EDS + (size_t)row*Kc + rank] = D;
      }
    }
    __builtin_amdgcn_wave_barrier();
  }
}

// ---------------- Kernel D2: S GEMM (8192x263)@(263x1024)+bias -> ns region --------
// A-tile staged k-major (stride 20, 16B-aligned) -> 4 broadcast ds_read_b128 per k.
__global__ __launch_bounds__(256) void kgemm_s(const float* __restrict__ ws,
                                               const float* __restrict__ wsw,
                                               const float* __restrict__ wsb,
                                               float* __restrict__ out) {
  __shared__ __align__(16) float Ast[SK*20];
  int tid = threadIdx.x;
  int row0 = blockIdx.x * 16;
  #pragma unroll
  for (int r = 0; r < 16; ++r)
    for (int k = tid; k < SK; k += 256)
      Ast[k*20 + r] = ws[WS_SIN + (size_t)(row0+r)*SK + k];
  __syncthreads();
  float acc[16][4] = {};
  #pragma unroll 2
  for (int k = 0; k < SK; ++k) {
    float4 a0 = *(const float4*)&Ast[k*20 + 0];
    float4 a1 = *(const float4*)&Ast[k*20 + 4];
    float4 a2 = *(const float4*)&Ast[k*20 + 8];
    float4 a3 = *(const float4*)&Ast[k*20 + 12];
    float b0 = wsw[(size_t)k*NSc + tid];
    float b1 = wsw[(size_t)k*NSc + tid + 256];
    float b2 = wsw[(size_t)k*NSc + tid + 512];
    float b3 = wsw[(size_t)k*NSc + tid + 768];
    float av[16] = {a0.x,a0.y,a0.z,a0.w, a1.x,a1.y,a1.z,a1.w,
                    a2.x,a2.y,a2.z,a2.w, a3.x,a3.y,a3.z,a3.w};
    #pragma unroll
    for (int r = 0; r < 16; ++r) {
      acc[r][0] = fmaf(av[r], b0, acc[r][0]);
      acc[r][1] = fmaf(av[r], b1, acc[r][1]);
      acc[r][2] = fmaf(av[r], b2, acc[r][2]);
      acc[r][3] = fmaf(av[r], b3, acc[r][3]);
    }
  }
  float bb0 = wsb[tid], bb1 = wsb[tid+256], bb2 = wsb[tid+512], bb3 = wsb[tid+768];
  #pragma unroll
  for (int r = 0; r < 16; ++r) {
    size_t o = OUT_NS + (size_t)(row0+r)*NSc + tid;
    out[o]     = acc[r][0] + bb0;
    out[o+256] = acc[r][1] + bb1;
    out[o+512] = acc[r][2] + bb2;
    out[o+768] = acc[r][3] + bb3;
  }
}

// ---------------- Kernel D3: V GEMM per d: (8192x256)@(256x256) -> nv region --------
__global__ __launch_bounds__(256) void kgemm_v(const float* __restrict__ avh,
                                               const float* __restrict__ wv,
                                               float* __restrict__ out) {
  __shared__ __align__(16) float Ast[256*20];
  int d = blockIdx.y;
  int row0 = blockIdx.x * 16;
  int tid = threadIdx.x;
  const float* Ad = avh + (size_t)d * Nn * 256;
  #pragma unroll
  for (int r = 0; r < 16; ++r)
    Ast[tid*20 + r] = Ad[(size_t)(row0+r)*256 + tid];
  __syncthreads();
  float acc[16] = {};
  #pragma unroll 4
  for (int k = 0; k < 256; ++k) {
    float4 a0 = *(const float4*)&Ast[k*20 + 0];
    float4 a1 = *(const float4*)&Ast[k*20 + 4];
    float4 a2 = *(const float4*)&Ast[k*20 + 8];
    float4 a3 = *(const float4*)&Ast[k*20 + 12];
    float bb = wv[(size_t)k*256 + tid];
    float av[16] = {a0.x,a0.y,a0.z,a0.w, a1.x,a1.y,a1.z,a1.w,
                    a2.x,a2.y,a2.z,a2.w, a3.x,a3.y,a3.z,a3.w};
    #pragma unroll
    for (int r = 0; r < 16; ++r) acc[r] = fmaf(av[r], bb, acc[r]);
  }
  #pragma unroll
  for (int r = 0; r < 16; ++r)
    out[OUT_NV + (size_t)(row0+r)*768 + (size_t)tid*3 + d] = acc[r];
}

// ---------------- Kernel C: edge features + edge GVP + edge LN + ei ----------------
__global__ __launch_bounds__(256) void kedge(const float* __restrict__ coords,
    const int* __restrict__ resid,
    const float* __restrict__ ewh, const float* __restrict__ eww,
    const float* __restrict__ ewb, const float* __restrict__ ewv,
    const float* __restrict__ elg, const float* __restrict__ elb,
    const float* __restrict__ ws, float* __restrict__ out) {
  __shared__ float w[35*32];
  __shared__ float wb[32], g[32], bb[32];
  int tid = threadIdx.x;
  for (int t = tid; t < 35*32; t += 256) w[t] = eww[t];
  if (tid < 32) { wb[tid] = ewb[tid]; g[tid] = elg[tid]; bb[tid] = elb[tid]; }
  __syncthreads();
  int e = blockIdx.x * 256 + tid;
  if (e >= NEc) return;
  int b = e / (Lc*Kc);
  int rem = e - b*(Lc*Kc);
  int i = rem / Kc;
  int row = b*Lc + i;
  const int* eix = (const int*)(ws + WS_EIX);
  int j = eix[e];
  float Dn = ws[WS_EDS + e];
  bool jok = ((unsigned)j < (unsigned)Lc);            // guard: poison/never-written -> invalid, not OOB
  bool valid = jok && (Dn < 5e7f) && (Dn < 5e9f);
  if (!valid) {
    #pragma unroll
    for (int c = 0; c < 32; ++c) out[OUT_ES + (size_t)e*32 + c] = 0.f;
    out[OUT_EV + (size_t)e*3 + 0] = 0.f;
    out[OUT_EV + (size_t)e*3 + 1] = 0.f;
    out[OUT_EV + (size_t)e*3 + 2] = 0.f;
    out[OUT_EI + e]       = -1.f;
    out[OUT_EI + NEc + e] = -1.f;
    return;
  }
  int dcl = resid[row] - resid[b*Lc + j];
  dcl = dcl < -32 ? -32 : (dcl > 32 ? 32 : dcl);
  float dpos = (float)dcl;
  float s[35];
  #pragma unroll
  for (int m = 0; m < 16; ++m) {
    float c = (20.f/15.f) * (float)m;
    float z = (Dn - c) * 0.8f;
    s[m] = expf(-z*z);
  }
  #pragma unroll
  for (int m = 0; m < 8; ++m) {
    float fr = expf((float)(2*m) * (-0.57564627324851148f));
    float ang = dpos * fr;
    s[16+m] = cosf(ang);
    s[24+m] = sinf(ang);
  }
  float csf = ws[WS_CMF + row];
  float cdf = ws[WS_CMF + b*Lc + j];
  s[32] = 1.f - csf; s[33] = 1.f - cdf;
  const float* Xb = coords + (size_t)b*Lc*9;
  float vx = Xb[i*9+3] - Xb[j*9+3];
  float vy = Xb[i*9+4] - Xb[j*9+4];
  float vz = Xb[i*9+5] - Xb[j*9+5];
  float ss2 = vx*vx + vy*vy + vz*vz;
  float inv = 1.f / sqrtf(ss2 + 1e-8f);
  float e0 = vx*inv, e1 = vy*inv, e2 = vz*inv;
  if (!isfinite(e0)) e0 = 0.f;
  if (!isfinite(e1)) e1 = 0.f;
  if (!isfinite(e2)) e2 = 0.f;
  float wh00 = ewh[0], wv00 = ewv[0];
  float vh0 = e0*wh00, vh1 = e1*wh00, vh2 = e2*wh00;
  s[34] = sqrtf(fmaxf(vh0*vh0 + vh1*vh1 + vh2*vh2, 1e-8f));
  float o[32]; float sm = 0.f;
  #pragma unroll
  for (int c = 0; c < 32; ++c) {
    float a = wb[c];
    #pragma unroll
    for (int q = 0; q < 35; ++q) a = fmaf(s[q], w[q*32 + c], a);
    o[c] = a; sm += a;
  }
  float mu = sm * (1.f/32.f);
  float sq = 0.f;
  #pragma unroll
  for (int c = 0; c < 32; ++c) { float dd = o[c]-mu; sq += dd*dd; }
  float isd = 1.f / sqrtf(sq*(1.f/32.f) + 1e-4f);
  float vo0 = vh0*wv00, vo1 = vh1*wv00, vo2 = vh2*wv00;
  float vn2 = fmaxf(vo0*vo0 + vo1*vo1 + vo2*vo2, 1e-8f);
  float ivn = 1.f / sqrtf(vn2);
  #pragma unroll
  for (int c = 0; c < 32; ++c)
    out[OUT_ES + (size_t)e*32 + c] = (o[c]-mu)*isd*g[c] + bb[c];
  out[OUT_EV + (size_t)e*3 + 0] = vo0*ivn;
  out[OUT_EV + (size_t)e*3 + 1] = vo1*ivn;
  out[OUT_EV + (size_t)e*3 + 2] = vo2*ivn;
  out[OUT_EI + e]       = (float)row;
  out[OUT_EI + NEc + e] = (float)(b*Lc + j);
}

// ---------------- Kernel D4: node LayerNorm + confidence RBF term ----------------
__global__ __launch_bounds__(256) void kln_node(const float* __restrict__ conf,
    const float* __restrict__ cw, const float* __restrict__ cb,
    const float* __restrict__ lg, const float* __restrict__ lb,
    float* __restrict__ out) {
  int n = blockIdx.x, tid = threadIdx.x;
  size_t base = OUT_NS + (size_t)n*NSc;
  float x0 = out[base + tid];
  float x1 = out[base + tid + 256];
  float x2 = out[base + tid + 512];
  float x3 = out[base + tid + 768];
  float sm = x0+x1+x2+x3;
  float sq = x0*x0+x1*x1+x2*x2+x3*x3;
  int lane = tid & 63, wid = tid >> 6;
  #pragma unroll
  for (int off = 32; off > 0; off >>= 1) { sm += __shfl_down(sm, off); sq += __shfl_down(sq, off); }
  __shared__ float rs[4], rq[4];
  if (lane == 0) { rs[wid] = sm; rq[wid] = sq; }
  __syncthreads();
  sm = rs[0]+rs[1]+rs[2]+rs[3];
  sq = rq[0]+rq[1]+rq[2]+rq[3];
  float mu = sm * (1.f/1024.f);
  float var = fmaxf(sq * (1.f/1024.f) - mu*mu, 0.f);
  float isd = 1.f / sqrtf(var + 1e-4f);
  float cf = conf[n];
  float rb[16];
  #pragma unroll
  for (int m = 0; m < 16; ++m) {
    float z = (cf - (float)m*(1.f/15.f)) * 16.f;
    rb[m] = expf(-z*z);
  }
  float xs_[4] = {x0, x1, x2, x3};
  #pragma unroll
  for (int q = 0; q < 4; ++q) {
    int c = tid + q*256;
    float t = cb[c];
    #pragma unroll
    for (int m = 0; m < 16; ++m) t = fmaf(rb[m], cw[m*1024 + c], t);
    out[base + c] = (xs_[q]-mu)*isd*lg[c] + lb[c] + t;
  }
}

// ---------------- Kernel D5: node vector norm epilogue ----------------
__global__ __launch_bounds__(256) void kvnorm(float* __restrict__ out) {
  int n = blockIdx.x, tid = threadIdx.x;
  size_t base = OUT_NV + (size_t)n*768;
  float v0 = out[base + tid*3 + 0];
  float v1 = out[base + tid*3 + 1];
  float v2 = out[base + tid*3 + 2];
  float vn2 = fmaxf(v0*v0 + v1*v1 + v2*v2, 1e-8f);
  int lane = tid & 63, wid = tid >> 6;
  float sm = vn2;
  #pragma unroll
  for (int off = 32; off > 0; off >>= 1) sm += __shfl_down(sm, off);
  __shared__ float rs[4];
  if (lane == 0) rs[wid] = sm;
  __syncthreads();
  sm = rs[0]+rs[1]+rs[2]+rs[3];
  float isd = 1.f / sqrtf(sm * (1.f/256.f));
  out[base + tid*3 + 0] = v0*isd;
  out[base + tid*3 + 1] = v1*isd;
  out[base + tid*3 + 2] = v2*isd;
}

extern "C" void kernel_launch(void* const* d_in, const int* in_sizes, int n_in,
                              void* d_out, int out_size, void* d_ws, size_t ws_size,
                              hipStream_t stream) {
  const float* coords         = (const float*)d_in[0];
  const unsigned char* cmask  = (const unsigned char*)d_in[1];
  const int* resid            = (const int*)d_in[2];
  const unsigned char* pmask  = (const unsigned char*)d_in[3];
  const float* conf           = (const float*)d_in[4];
  const float* nwh            = (const float*)d_in[5];
  const float* nww            = (const float*)d_in[6];
  const float* nwb            = (const float*)d_in[7];
  const float* nwv            = (const float*)d_in[8];
  const float* nlg            = (const float*)d_in[9];
  const float* nlb            = (const float*)d_in[10];
  const float* ewh            = (const float*)d_in[11];
  const float* eww            = (const float*)d_in[12];
  const float* ewb            = (const float*)d_in[13];
  const float* ewv            = (const float*)d_in[14];
  const float* elg            = (const float*)d_in[15];
  const float* elb            = (const float*)d_in[16];
  const float* cw             = (const float*)d_in[17];
  const float* cb             = (const float*)d_in[18];
  float* out = (float*)d_out;
  float* ws  = (float*)d_ws;
  float* avh = out + OUT_ES;   // stage vh in es output region; consumed before kedge writes es

  kmask<<<1, 1024, 0, stream>>>(cmask, ws);
  knode_geom<<<(Nn+255)/256, 256, 0, stream>>>(coords, ws);
  kgvp_pre<<<Nn, 256, 0, stream>>>(ws, nwh, avh);
  ktopk<<<Nn/16, 256, 0, stream>>>(coords, resid, pmask, ws);
  kgemm_s<<<Nn/16, 256, 0, stream>>>(ws, nww, nwb, out);
  kgemm_v<<<dim3(Nn/16, 3), 256, 0, stream>>>(avh, nwv, out);
  kedge<<<NEc/256, 256, 0, stream>>>(coords, resid, ewh, eww, ewb, ewv, elg, elb, ws, out);
  kln_node<<<Nn, 256, 0, stream>>>(conf, cw, cb, nlg, nlb, out);
  kvnorm<<<Nn, 256, 0, stream>>>(out);
}

// Round 7
// 488.990 us; speedup vs baseline: 1.9622x; 1.1341x over previous
//
#include <hip/hip_runtime.h>
#include <math.h>

// ---- problem constants ----
constexpr int Bc = 4, Lc = 2048, Kc = 30;
constexpr int Nn = Bc * Lc;            // 8192 nodes
constexpr int NSc = 1024, NVc = 256;
constexpr int NEc = Nn * Kc;           // 245760 edges
constexpr int SK = 263;                // 7 + 256 scalar GVP input dim

// ---- d_out float offsets (outputs concatenated flat in return order) ----
constexpr size_t OUT_NS = 0;                                  // (8192,1024)
constexpr size_t OUT_NV = (size_t)Nn * NSc;                   // (8192,256,3)
constexpr size_t OUT_ES = OUT_NV + (size_t)Nn * NVc * 3;      // (245760,32)
constexpr size_t OUT_EV = OUT_ES + (size_t)NEc * 32;          // (245760,1,3)
constexpr size_t OUT_EI = OUT_EV + (size_t)NEc * 3;           // (2,245760) as float

// ---- workspace float offsets ----
constexpr size_t WS_SIN = 0;                                  // (8192,263) s_in
constexpr size_t WS_NDV = WS_SIN + (size_t)Nn * SK;           // (8192,9) node_v
constexpr size_t WS_EIX = WS_NDV + (size_t)Nn * 9;            // (245760) int E_idx
constexpr size_t WS_EDS = WS_EIX + (size_t)NEc;               // (245760) E_dist
constexpr size_t WS_CMF = WS_EDS + (size_t)NEc;               // (8192) canonical coord_mask float

__device__ __forceinline__ void norml3(float& x, float& y, float& z) {
  float ss = x*x + y*y + z*z;
  float inv = 1.0f / sqrtf(ss + 1e-8f);
  x *= inv; y *= inv; z *= inv;
}

// ---------------- Kernel M: canonicalize coord_mask (bytes-vs-int32 autodetect) ----
// All blocks scan the SAME first 1KB (safe for both layouts): byte-format has
// random nonzeros at p%4!=0 (P[all zero]=2^-768); int32-format has none there.
__global__ __launch_bounds__(256) void kmask(const unsigned char* __restrict__ cm,
                                             float* __restrict__ ws) {
  __shared__ int flag;
  if (threadIdx.x == 0) flag = 0;
  __syncthreads();
  int any = 0;
  for (int p = threadIdx.x; p < 1024; p += 256)
    if (p & 3) any |= cm[p];
  if (any) atomicOr(&flag, 1);
  __syncthreads();
  bool bytefmt = (flag != 0);
  int n = blockIdx.x * 256 + threadIdx.x;
  unsigned char v = bytefmt ? cm[n] : cm[4*n];  // LE low byte of int32 0/1
  ws[WS_CMF + n] = v ? 1.f : 0.f;
}

// ---------------- Kernel A: per-node geometric features ----------------
__global__ __launch_bounds__(256) void knode_geom(const float* __restrict__ coords,
                                                  float* __restrict__ ws) {
  int n = blockIdx.x * 256 + threadIdx.x;
  if (n >= Nn) return;
  int b = n / Lc, l = n % Lc;
  const float* Xb = coords + (size_t)b * Lc * 9;
  float ax[7][3];
  #pragma unroll
  for (int m = 0; m < 7; ++m) {
    int t = 3*l + m - 2;
    if (t >= 0 && t < 3*Lc) { ax[m][0]=Xb[t*3+0]; ax[m][1]=Xb[t*3+1]; ax[m][2]=Xb[t*3+2]; }
    else { ax[m][0]=0.f; ax[m][1]=0.f; ax[m][2]=0.f; }
  }
  float U[5][3];
  #pragma unroll
  for (int mi = 0; mi < 5; ++mi) {
    int t = 3*l - 1 + mi;
    if (t >= 0 && t <= 3*Lc - 2) {
      float x = ax[mi+2][0]-ax[mi+1][0], y = ax[mi+2][1]-ax[mi+1][1], z = ax[mi+2][2]-ax[mi+1][2];
      norml3(x,y,z);
      U[mi][0]=x; U[mi][1]=y; U[mi][2]=z;
    } else { U[mi][0]=0.f; U[mi][1]=0.f; U[mi][2]=0.f; }
  }
  float cph[3], sph[3];
  #pragma unroll
  for (int a = 0; a < 3; ++a) {
    int t = 3*l + a - 1;
    if (t < 0 || t > 3*Lc - 4) { cph[a] = 1.f; sph[a] = 0.f; continue; }
    const float *u2 = U[a], *u1 = U[a+1], *u0 = U[a+2];
    float n2x = u2[1]*u1[2]-u2[2]*u1[1], n2y = u2[2]*u1[0]-u2[0]*u1[2], n2z = u2[0]*u1[1]-u2[1]*u1[0];
    norml3(n2x,n2y,n2z);
    float n1x = u1[1]*u0[2]-u1[2]*u0[1], n1y = u1[2]*u0[0]-u1[0]*u0[2], n1z = u1[0]*u0[1]-u1[1]*u0[0];
    norml3(n1x,n1y,n1z);
    float cd = n2x*n1x + n2y*n1y + n2z*n1z;
    cd = fminf(fmaxf(cd, -1.f + 1e-7f), 1.f - 1e-7f);
    float dt = u2[0]*n1x + u2[1]*n1y + u2[2]*n1z;
    float sg = (dt > 0.f) ? 1.f : ((dt < 0.f) ? -1.f : 0.f);
    float D = sg * acosf(cd);
    cph[a] = cosf(D); sph[a] = sinf(D);
  }
  float fx=0.f,fy=0.f,fz=0.f, kx=0.f,ky=0.f,kz=0.f;
  if (l < Lc-1) { fx=ax[6][0]-ax[3][0]; fy=ax[6][1]-ax[3][1]; fz=ax[6][2]-ax[3][2]; norml3(fx,fy,fz); }
  if (l > 0)    { kx=ax[0][0]-ax[3][0]; ky=ax[0][1]-ax[3][1]; kz=ax[0][2]-ax[3][2]; norml3(kx,ky,kz); }
  float cx=ax[4][0]-ax[3][0], cy=ax[4][1]-ax[3][1], cz=ax[4][2]-ax[3][2]; norml3(cx,cy,cz);
  float nx=ax[2][0]-ax[3][0], ny=ax[2][1]-ax[3][1], nz=ax[2][2]-ax[3][2]; norml3(nx,ny,nz);
  float bix=cx+nx, biy=cy+ny, biz=cz+nz; norml3(bix,biy,biz);
  float px=cy*nz-cz*ny, py=cz*nx-cx*nz, pz=cx*ny-cy*nx; norml3(px,py,pz);
  const float c1 = 0.57735026f, c2 = 0.81649658f;
  float sx = -bix*c1 - px*c2, sy = -biy*c1 - py*c2, sz = -biz*c1 - pz*c2;

  float cmf = ws[WS_CMF + n];
  float* sr = ws + WS_SIN + (size_t)n * SK;
  sr[0]=cph[0]; sr[1]=cph[1]; sr[2]=cph[2]; sr[3]=sph[0]; sr[4]=sph[1]; sr[5]=sph[2]; sr[6]=cmf;
  float* vr = ws + WS_NDV + (size_t)n * 9;
  vr[0]=fx; vr[1]=fy; vr[2]=fz; vr[3]=kx; vr[4]=ky; vr[5]=kz; vr[6]=sx; vr[7]=sy; vr[8]=sz;
}

// ---------------- Kernel D1: vh = wh^T * node_v ; vn -> s_in[7..262] ----------------
__global__ __launch_bounds__(256) void kgvp_pre(float* __restrict__ ws,
                                                const float* __restrict__ wh,
                                                float* __restrict__ avh) {
  int n = blockIdx.x, h = threadIdx.x;
  const float* v = ws + WS_NDV + (size_t)n * 9;
  float w0 = wh[h], w1 = wh[256+h], w2 = wh[512+h];
  float vh0 = v[0]*w0 + v[3]*w1 + v[6]*w2;
  float vh1 = v[1]*w0 + v[4]*w1 + v[7]*w2;
  float vh2 = v[2]*w0 + v[5]*w1 + v[8]*w2;
  avh[(size_t)0*Nn*256 + (size_t)n*256 + h] = vh0;
  avh[(size_t)1*Nn*256 + (size_t)n*256 + h] = vh1;
  avh[(size_t)2*Nn*256 + (size_t)n*256 + h] = vh2;
  ws[WS_SIN + (size_t)n*SK + 7 + h] = sqrtf(fmaxf(vh0*vh0 + vh1*vh1 + vh2*vh2, 1e-8f));
}

// ---------------- Kernel B: wave-autonomous exact top-30 radix select ----------
__global__ __launch_bounds__(256) void ktopk(const float* __restrict__ coords,
                                             const int* __restrict__ resid,
                                             const unsigned char* __restrict__ pmask,
                                             float* __restrict__ ws) {
  __shared__ float xsx[Lc], xsy[Lc], xsz[Lc];
  __shared__ int   res[Lc];
  __shared__ unsigned cmw[Lc/32], rmw[Lc/32];
  __shared__ unsigned hist[4][256];
  __shared__ unsigned long long cbuf[4][256];
  int tid = threadIdx.x, lane = tid & 63, wid = tid >> 6;
  int row0 = blockIdx.x * 16;
  int b = row0 >> 11;
  int i0 = row0 & (Lc - 1);
  const float* Xb = coords + (size_t)b * Lc * 9;
  for (int it = 0; it < Lc/256; ++it) {
    int j = tid + 256*it;
    xsx[j] = Xb[j*9+3]; xsy[j] = Xb[j*9+4]; xsz[j] = Xb[j*9+5];
    res[j] = resid[b*Lc + j];
    unsigned long long mcm = __ballot(ws[WS_CMF + b*Lc + j] != 0.f);
    unsigned long long mrm = __ballot(pmask[b*Lc + j] == 0);
    if (lane == 0) {
      int w0 = j >> 5;
      cmw[w0] = (unsigned)mcm; cmw[w0+1] = (unsigned)(mcm >> 32);
      rmw[w0] = (unsigned)mrm; rmw[w0+1] = (unsigned)(mrm >> 32);
    }
  }
  __syncthreads();
  int* eix = (int*)(ws + WS_EIX);
  unsigned long long lmask_lt = (1ULL << lane) - 1ULL;
  for (int rr = 0; rr < 4; ++rr) {
    int i = i0 + wid*4 + rr;
    int row = row0 + wid*4 + rr;
    float xi0 = xsx[i], xi1 = xsy[i], xi2 = xsz[i];
    float cmi = ((cmw[i>>5] >> (i&31)) & 1) ? 1.f : 0.f;
    float rmi = ((rmw[i>>5] >> (i&31)) & 1) ? 1.f : 0.f;
    int ri = res[i];
    unsigned long long key[32];
    #pragma unroll
    for (int m = 0; m < 32; ++m) {
      int j = lane + 64*m;
      float cmj = ((cmw[j>>5] >> (j&31)) & 1) ? 1.f : 0.f;
      float rmj = ((rmw[j>>5] >> (j&31)) & 1) ? 1.f : 0.f;
      float dx = __fsub_rn(xi0, xsx[j]);
      float dy = __fsub_rn(xi1, xsy[j]);
      float dz = __fsub_rn(xi2, xsz[j]);
      float ss = __fadd_rn(__fadd_rn(__fmul_rn(dx,dx), __fmul_rn(dy,dy)), __fmul_rn(dz,dz));
      float dist = __fsqrt_rn(__fadd_rn(ss, 1e-8f));
      float cm2 = __fmul_rn(cmi, cmj);
      float D = __fmul_rn(cm2, dist);
      int ad = ri - res[j]; ad = ad < 0 ? -ad : ad;
      float covm = (ad <= 3) ? 0.f : 1.f;
      float dseq = (float)(i >= j ? i - j : j - i);
      float t1 = __fmul_rn(__fsub_rn(1.f, cm2), __fadd_rn(1e8f, __fmul_rn(dseq, 1e6f)));
      float rm2 = __fmul_rn(rmi, rmj);
      float t2 = __fmul_rn(__fsub_rn(1.f, rm2), 1e10f);
      float adj = __fadd_rn(__fadd_rn(__fmul_rn(D, covm), t1), t2);
      key[m] = ((unsigned long long)__float_as_uint(adj) << 32) | (unsigned int)j;
    }
    unsigned cut16;
    {
      hist[wid][lane*4+0] = 0; hist[wid][lane*4+1] = 0;
      hist[wid][lane*4+2] = 0; hist[wid][lane*4+3] = 0;
      __builtin_amdgcn_wave_barrier();
      #pragma unroll
      for (int m = 0; m < 32; ++m) atomicAdd(&hist[wid][(unsigned)(key[m] >> 56)], 1u);
      __builtin_amdgcn_wave_barrier();
      unsigned h0 = hist[wid][lane*4+0], h1 = hist[wid][lane*4+1];
      unsigned h2 = hist[wid][lane*4+2], h3 = hist[wid][lane*4+3];
      unsigned s = h0+h1+h2+h3;
      unsigned v = s;
      #pragma unroll
      for (int off = 1; off < 64; off <<= 1) { unsigned o = __shfl_up(v, off); if (lane >= off) v += o; }
      unsigned excl = v - s;
      unsigned target = Kc;
      unsigned inc0 = excl+h0, inc1 = inc0+h1, inc2 = inc1+h2, inc3 = inc2+h3;
      bool cross = (inc3 >= target) && (excl < target);
      unsigned cb, nb;
      if      (inc0 >= target) { cb = 0; nb = excl; }
      else if (inc1 >= target) { cb = 1; nb = inc0; }
      else if (inc2 >= target) { cb = 2; nb = inc1; }
      else                     { cb = 3; nb = inc2; }
      int src = __ffsll((long long)__ballot(cross)) - 1;
      if (src < 0) src = 0;
      unsigned c1  = __shfl((unsigned)(lane*4) + cb, src);
      unsigned nb1 = __shfl(nb, src);
      hist[wid][lane*4+0] = 0; hist[wid][lane*4+1] = 0;
      hist[wid][lane*4+2] = 0; hist[wid][lane*4+3] = 0;
      __builtin_amdgcn_wave_barrier();
      #pragma unroll
      for (int m = 0; m < 32; ++m)
        if ((unsigned)(key[m] >> 56) == c1) atomicAdd(&hist[wid][(unsigned)(key[m] >> 48) & 0xFF], 1u);
      __builtin_amdgcn_wave_barrier();
      h0 = hist[wid][lane*4+0]; h1 = hist[wid][lane*4+1];
      h2 = hist[wid][lane*4+2]; h3 = hist[wid][lane*4+3];
      s = h0+h1+h2+h3;
      v = s;
      #pragma unroll
      for (int off = 1; off < 64; off <<= 1) { unsigned o = __shfl_up(v, off); if (lane >= off) v += o; }
      excl = v - s;
      target = Kc - nb1;
      inc0 = excl+h0; inc1 = inc0+h1; inc2 = inc1+h2; inc3 = inc2+h3;
      cross = (inc3 >= target) && (excl < target);
      if      (inc0 >= target) cb = 0;
      else if (inc1 >= target) cb = 1;
      else if (inc2 >= target) cb = 2;
      else                     cb = 3;
      src = __ffsll((long long)__ballot(cross)) - 1;
      if (src < 0) src = 0;
      cut16 = __shfl((c1 << 8) | ((unsigned)(lane*4) + cb), src);
    }
    unsigned base = 0;
    #pragma unroll
    for (int m = 0; m < 32; ++m) {
      bool pred = ((unsigned)(key[m] >> 48) <= cut16);
      unsigned long long bal = __ballot(pred);
      if (pred) {
        unsigned pos = base + (unsigned)__popcll(bal & lmask_lt);
        if (pos < 256u) cbuf[wid][pos] = key[m];
      }
      base += (unsigned)__popcll(bal);
    }
    unsigned M = base < 256u ? base : 256u;
    __builtin_amdgcn_wave_barrier();
    for (unsigned idx = (unsigned)lane; idx < M; idx += 64u) {
      unsigned long long k0 = cbuf[wid][idx];
      int rank = 0;
      for (unsigned t = 0; t < M; ++t) rank += (cbuf[wid][t] < k0) ? 1 : 0;
      if (rank < Kc) {
        int j = (int)(k0 & 0xffffffffULL);
        float cmj = ((cmw[j>>5] >> (j&31)) & 1) ? 1.f : 0.f;
        float dx = __fsub_rn(xi0, xsx[j]);
        float dy = __fsub_rn(xi1, xsy[j]);
        float dz = __fsub_rn(xi2, xsz[j]);
        float ss2 = __fadd_rn(__fadd_rn(__fmul_rn(dx,dx), __fmul_rn(dy,dy)), __fmul_rn(dz,dz));
        float dist = __fsqrt_rn(__fadd_rn(ss2, 1e-8f));
        float D = __fmul_rn(__fmul_rn(cmi, cmj), dist);
        eix[(size_t)row*Kc + rank] = j;
        ws[WS_EDS + (size_t)row*Kc + rank] = D;
      }
    }
    __builtin_amdgcn_wave_barrier();
  }
}

// ---------------- Kernel D2: S GEMM (8192x263)@(263x1024)+bias -> ns region --------
// 8-row tiles (grid 1024 = 4 blocks/CU, 16 waves/CU), A k-major stride 8 in LDS
// (2 broadcast ds_read_b128/k), manual B prefetch pipeline.
__global__ __launch_bounds__(256) void kgemm_s(const float* __restrict__ ws,
                                               const float* __restrict__ wsw,
                                               const float* __restrict__ wsb,
                                               float* __restrict__ out) {
  __shared__ __align__(16) float Ast[SK*8];
  int tid = threadIdx.x;
  int row0 = blockIdx.x * 8;
  #pragma unroll
  for (int r = 0; r < 8; ++r)
    for (int k = tid; k < SK; k += 256)
      Ast[k*8 + r] = ws[WS_SIN + (size_t)(row0+r)*SK + k];
  __syncthreads();
  float acc[8][4] = {};
  float b0 = wsw[tid], b1 = wsw[tid+256], b2 = wsw[tid+512], b3 = wsw[tid+768];
  for (int k = 0; k < SK-1; ++k) {
    float c0 = b0, c1 = b1, c2 = b2, c3 = b3;
    const float* bp = wsw + (size_t)(k+1)*NSc + tid;
    b0 = bp[0]; b1 = bp[256]; b2 = bp[512]; b3 = bp[768];
    float4 a0 = *(const float4*)&Ast[k*8 + 0];
    float4 a1 = *(const float4*)&Ast[k*8 + 4];
    float av[8] = {a0.x,a0.y,a0.z,a0.w, a1.x,a1.y,a1.z,a1.w};
    #pragma unroll
    for (int r = 0; r < 8; ++r) {
      acc[r][0] = fmaf(av[r], c0, acc[r][0]);
      acc[r][1] = fmaf(av[r], c1, acc[r][1]);
      acc[r][2] = fmaf(av[r], c2, acc[r][2]);
      acc[r][3] = fmaf(av[r], c3, acc[r][3]);
    }
  }
  {
    int k = SK-1;
    float4 a0 = *(const float4*)&Ast[k*8 + 0];
    float4 a1 = *(const float4*)&Ast[k*8 + 4];
    float av[8] = {a0.x,a0.y,a0.z,a0.w, a1.x,a1.y,a1.z,a1.w};
    #pragma unroll
    for (int r = 0; r < 8; ++r) {
      acc[r][0] = fmaf(av[r], b0, acc[r][0]);
      acc[r][1] = fmaf(av[r], b1, acc[r][1]);
      acc[r][2] = fmaf(av[r], b2, acc[r][2]);
      acc[r][3] = fmaf(av[r], b3, acc[r][3]);
    }
  }
  float bb0 = wsb[tid], bb1 = wsb[tid+256], bb2 = wsb[tid+512], bb3 = wsb[tid+768];
  #pragma unroll
  for (int r = 0; r < 8; ++r) {
    size_t o = OUT_NS + (size_t)(row0+r)*NSc + tid;
    out[o]     = acc[r][0] + bb0;
    out[o+256] = acc[r][1] + bb1;
    out[o+512] = acc[r][2] + bb2;
    out[o+768] = acc[r][3] + bb3;
  }
}

// ---------------- Kernel D3: V GEMM fused with vector-norm epilogue --------------
// 16 rows x 256 cols x all 3 dims per block. Wave = 64 col-lanes (4 cols each),
// row-group = wave id (4 rows each). A-frag: 1 broadcast ds_read_b128 per dim.
// B: one coalesced float4 per k (prefetched). Epilogue: butterfly-reduce row
// |v|^2 across the wave, scale, contiguous 48B/lane store. Replaces kvnorm.
__global__ __launch_bounds__(256) void kgemm_v(const float* __restrict__ avh,
                                               const float* __restrict__ wv,
                                               float* __restrict__ out) {
  __shared__ __align__(16) float Ast[3*256*20];
  int tid = threadIdx.x;
  int lane = tid & 63, rg = tid >> 6;
  int row0 = blockIdx.x * 16;
  int c0 = lane * 4;
  #pragma unroll
  for (int d = 0; d < 3; ++d)
    #pragma unroll
    for (int r = 0; r < 16; ++r)
      Ast[d*5120 + tid*20 + r] = avh[(size_t)d*Nn*256 + (size_t)(row0+r)*256 + tid];
  __syncthreads();
  float acc[4][4][3] = {};   // [row][col][dim]
  int r4 = rg * 4;
  float4 bn = *(const float4*)&wv[c0];
  for (int k = 0; k < 255; ++k) {
    float4 bcur = bn;
    bn = *(const float4*)&wv[(size_t)(k+1)*256 + c0];
    float4 a0 = *(const float4*)&Ast[0*5120 + k*20 + r4];
    float4 a1 = *(const float4*)&Ast[1*5120 + k*20 + r4];
    float4 a2 = *(const float4*)&Ast[2*5120 + k*20 + r4];
    float av0[4] = {a0.x,a0.y,a0.z,a0.w};
    float av1[4] = {a1.x,a1.y,a1.z,a1.w};
    float av2[4] = {a2.x,a2.y,a2.z,a2.w};
    float bv[4] = {bcur.x,bcur.y,bcur.z,bcur.w};
    #pragma unroll
    for (int r = 0; r < 4; ++r)
      #pragma unroll
      for (int q = 0; q < 4; ++q) {
        acc[r][q][0] = fmaf(av0[r], bv[q], acc[r][q][0]);
        acc[r][q][1] = fmaf(av1[r], bv[q], acc[r][q][1]);
        acc[r][q][2] = fmaf(av2[r], bv[q], acc[r][q][2]);
      }
  }
  {
    int k = 255;
    float4 a0 = *(const float4*)&Ast[0*5120 + k*20 + r4];
    float4 a1 = *(const float4*)&Ast[1*5120 + k*20 + r4];
    float4 a2 = *(const float4*)&Ast[2*5120 + k*20 + r4];
    float av0[4] = {a0.x,a0.y,a0.z,a0.w};
    float av1[4] = {a1.x,a1.y,a1.z,a1.w};
    float av2[4] = {a2.x,a2.y,a2.z,a2.w};
    float bv[4] = {bn.x,bn.y,bn.z,bn.w};
    #pragma unroll
    for (int r = 0; r < 4; ++r)
      #pragma unroll
      for (int q = 0; q < 4; ++q) {
        acc[r][q][0] = fmaf(av0[r], bv[q], acc[r][q][0]);
        acc[r][q][1] = fmaf(av1[r], bv[q], acc[r][q][1]);
        acc[r][q][2] = fmaf(av2[r], bv[q], acc[r][q][2]);
      }
  }
  // fused vector-norm: per row, mean over 256 h of max(|v_h|^2, 1e-8)
  #pragma unroll
  for (int r = 0; r < 4; ++r) {
    float p = 0.f;
    #pragma unroll
    for (int q = 0; q < 4; ++q) {
      float s2 = acc[r][q][0]*acc[r][q][0] + acc[r][q][1]*acc[r][q][1] + acc[r][q][2]*acc[r][q][2];
      p += fmaxf(s2, 1e-8f);
    }
    #pragma unroll
    for (int off = 1; off < 64; off <<= 1) p += __shfl_xor(p, off);
    float isd = 1.f / sqrtf(p * (1.f/256.f));
    int row = row0 + r4 + r;
    size_t o = OUT_NV + (size_t)row*768 + (size_t)c0*3;
    float4 f0 = {acc[r][0][0]*isd, acc[r][0][1]*isd, acc[r][0][2]*isd, acc[r][1][0]*isd};
    float4 f1 = {acc[r][1][1]*isd, acc[r][1][2]*isd, acc[r][2][0]*isd, acc[r][2][1]*isd};
    float4 f2 = {acc[r][2][2]*isd, acc[r][3][0]*isd, acc[r][3][1]*isd, acc[r][3][2]*isd};
    *(float4*)&out[o+0] = f0;
    *(float4*)&out[o+4] = f1;
    *(float4*)&out[o+8] = f2;
  }
}

// ---------------- Kernel C: edge features + edge GVP + edge LN + ei ----------------
__global__ __launch_bounds__(256) void kedge(const float* __restrict__ coords,
    const int* __restrict__ resid,
    const float* __restrict__ ewh, const float* __restrict__ eww,
    const float* __restrict__ ewb, const float* __restrict__ ewv,
    const float* __restrict__ elg, const float* __restrict__ elb,
    const float* __restrict__ ws, float* __restrict__ out) {
  __shared__ float w[35*32];
  __shared__ float wb[32], g[32], bb[32];
  int tid = threadIdx.x;
  for (int t = tid; t < 35*32; t += 256) w[t] = eww[t];
  if (tid < 32) { wb[tid] = ewb[tid]; g[tid] = elg[tid]; bb[tid] = elb[tid]; }
  __syncthreads();
  int e = blockIdx.x * 256 + tid;
  if (e >= NEc) return;
  int b = e / (Lc*Kc);
  int rem = e - b*(Lc*Kc);
  int i = rem / Kc;
  int row = b*Lc + i;
  const int* eix = (const int*)(ws + WS_EIX);
  int j = eix[e];
  float Dn = ws[WS_EDS + e];
  bool jok = ((unsigned)j < (unsigned)Lc);
  bool valid = jok && (Dn < 5e7f) && (Dn < 5e9f);
  if (!valid) {
    #pragma unroll
    for (int c = 0; c < 32; ++c) out[OUT_ES + (size_t)e*32 + c] = 0.f;
    out[OUT_EV + (size_t)e*3 + 0] = 0.f;
    out[OUT_EV + (size_t)e*3 + 1] = 0.f;
    out[OUT_EV + (size_t)e*3 + 2] = 0.f;
    out[OUT_EI + e]       = -1.f;
    out[OUT_EI + NEc + e] = -1.f;
    return;
  }
  int dcl = resid[row] - resid[b*Lc + j];
  dcl = dcl < -32 ? -32 : (dcl > 32 ? 32 : dcl);
  float dpos = (float)dcl;
  float s[35];
  #pragma unroll
  for (int m = 0; m < 16; ++m) {
    float c = (20.f/15.f) * (float)m;
    float z = (Dn - c) * 0.8f;
    s[m] = expf(-z*z);
  }
  #pragma unroll
  for (int m = 0; m < 8; ++m) {
    float fr = expf((float)(2*m) * (-0.57564627324851148f));
    float ang = dpos * fr;
    s[16+m] = cosf(ang);
    s[24+m] = sinf(ang);
  }
  float csf = ws[WS_CMF + row];
  float cdf = ws[WS_CMF + b*Lc + j];
  s[32] = 1.f - csf; s[33] = 1.f - cdf;
  const float* Xb = coords + (size_t)b*Lc*9;
  float vx = Xb[i*9+3] - Xb[j*9+3];
  float vy = Xb[i*9+4] - Xb[j*9+4];
  float vz = Xb[i*9+5] - Xb[j*9+5];
  float ss2 = vx*vx + vy*vy + vz*vz;
  float inv = 1.f / sqrtf(ss2 + 1e-8f);
  float e0 = vx*inv, e1 = vy*inv, e2 = vz*inv;
  if (!isfinite(e0)) e0 = 0.f;
  if (!isfinite(e1)) e1 = 0.f;
  if (!isfinite(e2)) e2 = 0.f;
  float wh00 = ewh[0], wv00 = ewv[0];
  float vh0 = e0*wh00, vh1 = e1*wh00, vh2 = e2*wh00;
  s[34] = sqrtf(fmaxf(vh0*vh0 + vh1*vh1 + vh2*vh2, 1e-8f));
  float o[32]; float sm = 0.f;
  #pragma unroll
  for (int c = 0; c < 32; ++c) {
    float a = wb[c];
    #pragma unroll
    for (int q = 0; q < 35; ++q) a = fmaf(s[q], w[q*32 + c], a);
    o[c] = a; sm += a;
  }
  float mu = sm * (1.f/32.f);
  float sq = 0.f;
  #pragma unroll
  for (int c = 0; c < 32; ++c) { float dd = o[c]-mu; sq += dd*dd; }
  float isd = 1.f / sqrtf(sq*(1.f/32.f) + 1e-4f);
  float vo0 = vh0*wv00, vo1 = vh1*wv00, vo2 = vh2*wv00;
  float vn2 = fmaxf(vo0*vo0 + vo1*vo1 + vo2*vo2, 1e-8f);
  float ivn = 1.f / sqrtf(vn2);
  #pragma unroll
  for (int c = 0; c < 32; ++c)
    out[OUT_ES + (size_t)e*32 + c] = (o[c]-mu)*isd*g[c] + bb[c];
  out[OUT_EV + (size_t)e*3 + 0] = vo0*ivn;
  out[OUT_EV + (size_t)e*3 + 1] = vo1*ivn;
  out[OUT_EV + (size_t)e*3 + 2] = vo2*ivn;
  out[OUT_EI + e]       = (float)row;
  out[OUT_EI + NEc + e] = (float)(b*Lc + j);
}

// ---------------- Kernel D4: node LayerNorm + confidence RBF term ----------------
__global__ __launch_bounds__(256) void kln_node(const float* __restrict__ conf,
    const float* __restrict__ cw, const float* __restrict__ cb,
    const float* __restrict__ lg, const float* __restrict__ lb,
    float* __restrict__ out) {
  int n = blockIdx.x, tid = threadIdx.x;
  size_t base = OUT_NS + (size_t)n*NSc;
  float x0 = out[base + tid];
  float x1 = out[base + tid + 256];
  float x2 = out[base + tid + 512];
  float x3 = out[base + tid + 768];
  float sm = x0+x1+x2+x3;
  float sq = x0*x0+x1*x1+x2*x2+x3*x3;
  int lane = tid & 63, wid = tid >> 6;
  #pragma unroll
  for (int off = 32; off > 0; off >>= 1) { sm += __shfl_down(sm, off); sq += __shfl_down(sq, off); }
  __shared__ float rs[4], rq[4];
  if (lane == 0) { rs[wid] = sm; rq[wid] = sq; }
  __syncthreads();
  sm = rs[0]+rs[1]+rs[2]+rs[3];
  sq = rq[0]+rq[1]+rq[2]+rq[3];
  float mu = sm * (1.f/1024.f);
  float var = fmaxf(sq * (1.f/1024.f) - mu*mu, 0.f);
  float isd = 1.f / sqrtf(var + 1e-4f);
  float cf = conf[n];
  float rb[16];
  #pragma unroll
  for (int m = 0; m < 16; ++m) {
    float z = (cf - (float)m*(1.f/15.f)) * 16.f;
    rb[m] = expf(-z*z);
  }
  float xs_[4] = {x0, x1, x2, x3};
  #pragma unroll
  for (int q = 0; q < 4; ++q) {
    int c = tid + q*256;
    float t = cb[c];
    #pragma unroll
    for (int m = 0; m < 16; ++m) t = fmaf(rb[m], cw[m*1024 + c], t);
    out[base + c] = (xs_[q]-mu)*isd*lg[c] + lb[c] + t;
  }
}

extern "C" void kernel_launch(void* const* d_in, const int* in_sizes, int n_in,
                              void* d_out, int out_size, void* d_ws, size_t ws_size,
                              hipStream_t stream) {
  const float* coords         = (const float*)d_in[0];
  const unsigned char* cmask  = (const unsigned char*)d_in[1];
  const int* resid            = (const int*)d_in[2];
  const unsigned char* pmask  = (const unsigned char*)d_in[3];
  const float* conf           = (const float*)d_in[4];
  const float* nwh            = (const float*)d_in[5];
  const float* nww            = (const float*)d_in[6];
  const float* nwb            = (const float*)d_in[7];
  const float* nwv            = (const float*)d_in[8];
  const float* nlg            = (const float*)d_in[9];
  const float* nlb            = (const float*)d_in[10];
  const float* ewh            = (const float*)d_in[11];
  const float* eww            = (const float*)d_in[12];
  const float* ewb            = (const float*)d_in[13];
  const float* ewv            = (const float*)d_in[14];
  const float* elg            = (const float*)d_in[15];
  const float* elb            = (const float*)d_in[16];
  const float* cw             = (const float*)d_in[17];
  const float* cb             = (const float*)d_in[18];
  float* out = (float*)d_out;
  float* ws  = (float*)d_ws;
  float* avh = out + OUT_ES;   // stage vh in es output region; consumed before kedge writes es

  kmask<<<Nn/256, 256, 0, stream>>>(cmask, ws);
  knode_geom<<<(Nn+255)/256, 256, 0, stream>>>(coords, ws);
  kgvp_pre<<<Nn, 256, 0, stream>>>(ws, nwh, avh);
  ktopk<<<Nn/16, 256, 0, stream>>>(coords, resid, pmask, ws);
  kgemm_s<<<Nn/8, 256, 0, stream>>>(ws, nww, nwb, out);
  kgemm_v<<<Nn/16, 256, 0, stream>>>(avh, nwv, out);
  kedge<<<NEc/256, 256, 0, stream>>>(coords, resid, ewh, eww, ewb, ewv, elg, elb, ws, out);
  kln_node<<<Nn, 256, 0, stream>>>(conf, cw, cb, nlg, nlb, out);
}